// Round 13
// baseline (1352.745 us; speedup 1.0000x reference)
//
#include <hip/hip_runtime.h>
#include <hip/hip_bf16.h>
#include <math.h>

#define D_DIM 256
#define NHEAD 8
#define HDIM 32
#define PATCH 256
#define NCLOUD 4
#define LPC 32768
#define NTOT (NCLOUD * LPC)
#define MLPD 512
#define PEHID 64
#define LN_EPS 1e-5f
#define NCHUNK 4
#define CROWS (NTOT / NCHUNK)   // 32768 rows per chunk

typedef unsigned long long u64;
typedef unsigned short u16;
typedef short bf16x8 __attribute__((ext_vector_type(8)));  // 8 bf16 (4 VGPRs)
typedef float f32x4 __attribute__((ext_vector_type(4)));

__device__ __forceinline__ u16 f2bf(float x) {
  unsigned u = __float_as_uint(x);
  u += 0x7fffu + ((u >> 16) & 1u);
  return (u16)(u >> 16);
}
__device__ __forceinline__ float bf2f(u16 u) {
  return __uint_as_float(((unsigned)u) << 16);
}

// async global->LDS DMA, 16B per lane; lds ptr must be wave-uniform base (+lane*16 implicit)
__device__ __forceinline__ void gload_lds16(const u16* g, u16* l) {
  __builtin_amdgcn_global_load_lds((const __attribute__((address_space(1))) void*)g,
                                   (__attribute__((address_space(3))) void*)l, 16, 0, 0);
}

// ---------------- per-cloud coordinate stats ----------------
__global__ __launch_bounds__(256) void stats_kernel(const float* __restrict__ coord,
                                                    float* __restrict__ stats) {
  const int c = blockIdx.x, t = threadIdx.x;
  float sm[3] = {0.f, 0.f, 0.f};
  float mn[3] = {1e30f, 1e30f, 1e30f};
  float mx[3] = {-1e30f, -1e30f, -1e30f};
  const float* cp = coord + (size_t)c * LPC * 3;
  for (int i = t; i < LPC; i += 256) {
#pragma unroll
    for (int a = 0; a < 3; a++) {
      float v = cp[(size_t)i * 3 + a];
      sm[a] += v;
      mn[a] = fminf(mn[a], v);
      mx[a] = fmaxf(mx[a], v);
    }
  }
  __shared__ float sb[256];
  float rsum[3], rmn[3], rmx[3];
#pragma unroll
  for (int a = 0; a < 3; a++) {
    sb[t] = sm[a]; __syncthreads();
    for (int s = 128; s > 0; s >>= 1) { if (t < s) sb[t] += sb[t + s]; __syncthreads(); }
    rsum[a] = sb[0]; __syncthreads();
    sb[t] = mn[a]; __syncthreads();
    for (int s = 128; s > 0; s >>= 1) { if (t < s) sb[t] = fminf(sb[t], sb[t + s]); __syncthreads(); }
    rmn[a] = sb[0]; __syncthreads();
    sb[t] = mx[a]; __syncthreads();
    for (int s = 128; s > 0; s >>= 1) { if (t < s) sb[t] = fmaxf(sb[t], sb[t + s]); __syncthreads(); }
    rmx[a] = sb[0]; __syncthreads();
  }
  if (t == 0) {
    float* st = stats + c * 16;
#pragma unroll
    for (int a = 0; a < 3; a++) {
      float mean = rsum[a] / (float)LPC;
      st[a] = mean;
      st[3 + a] = fmaxf(fmaxf(rmx[a] - mean, mean - rmn[a]), 1e-6f);
      st[6 + a] = rmn[a];
      st[9 + a] = fmaxf(rmx[a] - rmn[a], 1e-6f);
    }
  }
}

// ---------------- serialization keys (bit-exact vs numpy; stable tie-break) ----------------
__global__ __launch_bounds__(256) void key_kernel(const float* __restrict__ coord,
                                                  const float* __restrict__ stats,
                                                  u64* __restrict__ keys) {
#pragma clang fp contract(off)
  const int g = blockIdx.x * 256 + threadIdx.x;
  const int c = g >> 15;
  const float* st = stats + c * 16;
  float k0 = (coord[(size_t)g * 3 + 0] - st[6]) / st[9];
  float k1 = (coord[(size_t)g * 3 + 1] - st[7]) / st[10];
  float k2 = (coord[(size_t)g * 3 + 2] - st[8]) / st[11];
  float key = k0 + 2.17f * k1;
  key = key + 3.31f * k2;
  keys[g] = ((u64)__float_as_uint(key) << 32) | (unsigned)(g & (LPC - 1));
}

// ---------------- bitonic sort: 8192-element LDS segments ----------------
__global__ __launch_bounds__(1024) void sort_local8_kernel(u64* __restrict__ keys) {
  __shared__ u64 s[8192];
  const int base = blockIdx.x * 8192;
  const int t = threadIdx.x;
  for (int i = t; i < 8192; i += 1024) s[i] = keys[base + i];
  __syncthreads();
  for (int k = 2; k <= 8192; k <<= 1) {
    for (int j = k >> 1; j > 0; j >>= 1) {
      for (int p = t; p < 4096; p += 1024) {
        int i = ((p & ~(j - 1)) << 1) | (p & (j - 1));
        int l = i | j;
        bool asc = (((base + i) & (LPC - 1)) & k) == 0;
        u64 a = s[i], bb = s[l];
        if (asc ? (a > bb) : (a < bb)) { s[i] = bb; s[l] = a; }
      }
      __syncthreads();
    }
  }
  for (int i = t; i < 8192; i += 1024) keys[base + i] = s[i];
}

__global__ __launch_bounds__(256) void sort_global_kernel(u64* __restrict__ keys, int k, int j) {
  int p = blockIdx.x * 256 + threadIdx.x;
  int i = ((p & ~(j - 1)) << 1) | (p & (j - 1));
  int l = i | j;
  bool asc = ((i & (LPC - 1)) & k) == 0;
  u64 a = keys[i], b = keys[l];
  if (asc ? (a > b) : (a < b)) { keys[i] = b; keys[l] = a; }
}

__global__ __launch_bounds__(1024) void sort_finish8_kernel(u64* __restrict__ keys, int k) {
  __shared__ u64 s[8192];
  const int base = blockIdx.x * 8192;
  const int t = threadIdx.x;
  for (int i = t; i < 8192; i += 1024) s[i] = keys[base + i];
  __syncthreads();
  for (int j = 4096; j > 0; j >>= 1) {
    for (int p = t; p < 4096; p += 1024) {
      int i = ((p & ~(j - 1)) << 1) | (p & (j - 1));
      int l = i | j;
      bool asc = (((base + i) & (LPC - 1)) & k) == 0;
      u64 a = s[i], bb = s[l];
      if (asc ? (a > bb) : (a < bb)) { s[i] = bb; s[l] = a; }
    }
    __syncthreads();
  }
  for (int i = t; i < 8192; i += 1024) keys[base + i] = s[i];
}

// ---------------- order + rank from sorted keys ----------------
__global__ __launch_bounds__(256) void rank_kernel(const u64* __restrict__ keys,
                                                   int* __restrict__ order,
                                                   int* __restrict__ rank) {
  const int g = blockIdx.x * 256 + threadIdx.x;
  const int src = (int)(unsigned)(keys[g] & 0xffffffffULL) + (g & ~(LPC - 1));
  order[g] = src;
  rank[src] = g;
}

// ---------------- weight transpose + fp32->bf16: dst[C][R] = src[R][C] ----------------
__global__ __launch_bounds__(256) void wtrans_kernel(const float* __restrict__ src,
                                                     u16* __restrict__ dst, int R, int C) {
  __shared__ float t[32][33];
  const int bx = blockIdx.x * 32, by = blockIdx.y * 32;
  const int lc = threadIdx.x & 31, lr = threadIdx.x >> 5;  // 8 rows per pass
  for (int i = 0; i < 32; i += 8) t[lr + i][lc] = src[(size_t)(by + lr + i) * C + bx + lc];
  __syncthreads();
  for (int i = 0; i < 32; i += 8)
    dst[(size_t)(bx + lr + i) * R + by + lc] = f2bf(t[lc][lr + i]);
}

// ---------------- H = relu(scs @ pw1 + pb1), bf16 [N][64] ----------------
__global__ __launch_bounds__(256) void h_kernel(const float* __restrict__ coord,
                                                const float* __restrict__ stats,
                                                const float* __restrict__ pw1,
                                                const float* __restrict__ pb1,
                                                u16* __restrict__ H) {
  const int idx = blockIdx.x * 256 + threadIdx.x;
  const int row = idx >> 6, j = idx & 63;
  const int c = row >> 15;
  const float* st = stats + c * 16;
  float s0 = (coord[(size_t)row * 3 + 0] - st[0]) / st[3];
  float s1 = (coord[(size_t)row * 3 + 1] - st[1]) / st[4];
  float s2 = (coord[(size_t)row * 3 + 2] - st[2]) / st[5];
  float h = pb1[j] + s0 * pw1[j] + s1 * pw1[64 + j] + s2 * pw1[128 + j];
  H[idx] = f2bf(fmaxf(h, 0.f));
}

// ---------------- pe row GEMM + fused add+LN_pre+LN1: 64 rows/block ----------------
// pe = H @ pw2T^T + b2 (K=64); t = feats + pe; xs[rank] = LN_pre(t); ln1[rank] = bf16(LN1)
__global__ __launch_bounds__(256, 3) void pe_row_kernel(
    const u16* __restrict__ H, const u16* __restrict__ pw2T,
    const float* __restrict__ pb2, const float* __restrict__ feats,
    const int* __restrict__ rank,
    const float* __restrict__ g0, const float* __restrict__ b0,
    const float* __restrict__ g1, const float* __restrict__ b1,
    float* __restrict__ xs, u16* __restrict__ ln1out) {
  __shared__ __align__(16) u16 Al[64 * 32];
  __shared__ __align__(16) u16 Bl[256 * 32];
  __shared__ float reds[2][4][64];
  const int tid = threadIdx.x;
  const int lane = tid & 63, wave = tid >> 6;
  const int l15 = lane & 15, l4 = lane >> 4;
  const size_t row0 = (size_t)blockIdx.x * 64;
  const u16* gA = H + (row0 + (tid >> 2)) * 64 + (tid & 3) * 8;
  u16* lA = Al + wave * 512;
  const u16* gB[4];
  u16* lB[4];
#pragma unroll
  for (int s = 0; s < 4; s++) {
    int q = s * 256 + tid;
    gB[s] = pw2T + (size_t)(q >> 2) * 64 + (q & 3) * 8;
    lB[s] = Bl + s * 2048 + wave * 512;
  }
  f32x4 acc[4][4];
#pragma unroll
  for (int i = 0; i < 4; i++)
#pragma unroll
    for (int j = 0; j < 4; j++) acc[i][j] = f32x4{0.f, 0.f, 0.f, 0.f};
#pragma unroll 1
  for (int k0 = 0; k0 < 64; k0 += 32) {
    gload_lds16(gA + k0, lA);
#pragma unroll
    for (int s = 0; s < 4; s++) gload_lds16(gB[s] + k0, lB[s]);
    __syncthreads();
    bf16x8 af[4], bfr[4];
#pragma unroll
    for (int rb = 0; rb < 4; rb++)
      af[rb] = *(const bf16x8*)&Al[(rb * 16 + l15) * 32 + l4 * 8];
#pragma unroll
    for (int cb = 0; cb < 4; cb++)
      bfr[cb] = *(const bf16x8*)&Bl[(wave * 64 + cb * 16 + l15) * 32 + l4 * 8];
#pragma unroll
    for (int rb = 0; rb < 4; rb++)
#pragma unroll
      for (int cb = 0; cb < 4; cb++)
        acc[rb][cb] = __builtin_amdgcn_mfma_f32_16x16x32_bf16(af[rb], bfr[cb], acc[rb][cb], 0, 0, 0);
    __syncthreads();
  }
  // t = feats + pe + b2  (keep t in acc)
#pragma unroll
  for (int rb = 0; rb < 4; rb++)
#pragma unroll
    for (int cb = 0; cb < 4; cb++)
#pragma unroll
      for (int r = 0; r < 4; r++) {
        size_t row = row0 + rb * 16 + l4 * 4 + r;
        int col = wave * 64 + cb * 16 + l15;
        acc[rb][cb][r] = feats[row * 256 + col] + acc[rb][cb][r] + pb2[col];
      }
  float ps[4][4], mean[4][4];
  // --- LN_pre: mean ---
#pragma unroll
  for (int rb = 0; rb < 4; rb++)
#pragma unroll
    for (int r = 0; r < 4; r++) {
      float v = acc[rb][0][r] + acc[rb][1][r] + acc[rb][2][r] + acc[rb][3][r];
#pragma unroll
      for (int oo = 1; oo < 16; oo <<= 1) v += __shfl_xor(v, oo);
      ps[rb][r] = v;
    }
  if (l15 == 0)
#pragma unroll
    for (int rb = 0; rb < 4; rb++)
#pragma unroll
      for (int r = 0; r < 4; r++) reds[0][wave][rb * 16 + l4 * 4 + r] = ps[rb][r];
  __syncthreads();
#pragma unroll
  for (int rb = 0; rb < 4; rb++)
#pragma unroll
    for (int r = 0; r < 4; r++) {
      int ri = rb * 16 + l4 * 4 + r;
      mean[rb][r] = (reds[0][0][ri] + reds[0][1][ri] + reds[0][2][ri] + reds[0][3][ri]) *
                    (1.f / 256.f);
    }
  // --- LN_pre: var ---
#pragma unroll
  for (int rb = 0; rb < 4; rb++)
#pragma unroll
    for (int r = 0; r < 4; r++) {
      float d0 = acc[rb][0][r] - mean[rb][r], d1 = acc[rb][1][r] - mean[rb][r];
      float d2 = acc[rb][2][r] - mean[rb][r], d3 = acc[rb][3][r] - mean[rb][r];
      float v = d0 * d0 + d1 * d1 + d2 * d2 + d3 * d3;
#pragma unroll
      for (int oo = 1; oo < 16; oo <<= 1) v += __shfl_xor(v, oo);
      ps[rb][r] = v;
    }
  if (l15 == 0)
#pragma unroll
    for (int rb = 0; rb < 4; rb++)
#pragma unroll
      for (int r = 0; r < 4; r++) reds[1][wave][rb * 16 + l4 * 4 + r] = ps[rb][r];
  __syncthreads();
  // y = LN_pre(t); write xs[rank]; keep y in acc
#pragma unroll
  for (int rb = 0; rb < 4; rb++)
#pragma unroll
    for (int r = 0; r < 4; r++) {
      int ri = rb * 16 + l4 * 4 + r;
      float var = (reds[1][0][ri] + reds[1][1][ri] + reds[1][2][ri] + reds[1][3][ri]) *
                  (1.f / 256.f);
      float inv = 1.f / sqrtf(var + LN_EPS);
      size_t row = row0 + ri;
      size_t dst = (size_t)rank[row];
#pragma unroll
      for (int cb = 0; cb < 4; cb++) {
        int col = wave * 64 + cb * 16 + l15;
        float y = (acc[rb][cb][r] - mean[rb][r]) * inv * g0[col] + b0[col];
        acc[rb][cb][r] = y;
        xs[dst * 256 + col] = y;
      }
    }
  // --- LN1: mean ---
#pragma unroll
  for (int rb = 0; rb < 4; rb++)
#pragma unroll
    for (int r = 0; r < 4; r++) {
      float v = acc[rb][0][r] + acc[rb][1][r] + acc[rb][2][r] + acc[rb][3][r];
#pragma unroll
      for (int oo = 1; oo < 16; oo <<= 1) v += __shfl_xor(v, oo);
      ps[rb][r] = v;
    }
  __syncthreads();  // ensure prior reds reads done before overwrite
  if (l15 == 0)
#pragma unroll
    for (int rb = 0; rb < 4; rb++)
#pragma unroll
      for (int r = 0; r < 4; r++) reds[0][wave][rb * 16 + l4 * 4 + r] = ps[rb][r];
  __syncthreads();
#pragma unroll
  for (int rb = 0; rb < 4; rb++)
#pragma unroll
    for (int r = 0; r < 4; r++) {
      int ri = rb * 16 + l4 * 4 + r;
      mean[rb][r] = (reds[0][0][ri] + reds[0][1][ri] + reds[0][2][ri] + reds[0][3][ri]) *
                    (1.f / 256.f);
    }
  // --- LN1: var ---
#pragma unroll
  for (int rb = 0; rb < 4; rb++)
#pragma unroll
    for (int r = 0; r < 4; r++) {
      float d0 = acc[rb][0][r] - mean[rb][r], d1 = acc[rb][1][r] - mean[rb][r];
      float d2 = acc[rb][2][r] - mean[rb][r], d3 = acc[rb][3][r] - mean[rb][r];
      float v = d0 * d0 + d1 * d1 + d2 * d2 + d3 * d3;
#pragma unroll
      for (int oo = 1; oo < 16; oo <<= 1) v += __shfl_xor(v, oo);
      ps[rb][r] = v;
    }
  if (l15 == 0)
#pragma unroll
    for (int rb = 0; rb < 4; rb++)
#pragma unroll
      for (int r = 0; r < 4; r++) reds[1][wave][rb * 16 + l4 * 4 + r] = ps[rb][r];
  __syncthreads();
#pragma unroll
  for (int rb = 0; rb < 4; rb++)
#pragma unroll
    for (int r = 0; r < 4; r++) {
      int ri = rb * 16 + l4 * 4 + r;
      float var = (reds[1][0][ri] + reds[1][1][ri] + reds[1][2][ri] + reds[1][3][ri]) *
                  (1.f / 256.f);
      float inv = 1.f / sqrtf(var + LN_EPS);
      size_t row = row0 + ri;
      size_t dst = (size_t)rank[row];
#pragma unroll
      for (int cb = 0; cb < 4; cb++) {
        int col = wave * 64 + cb * 16 + l15;
        ln1out[dst * 256 + col] =
            f2bf((acc[rb][cb][r] - mean[rb][r]) * inv * g1[col] + b1[col]);
      }
    }
}

// ---------------- MFMA GEMM (m97 structure): C[M x Ko] = act(A@Wt^T + bias) ----------------
// MODE: 0 fp32 store, 1 fp32 resid +=, 2 bf16 store
template <int K, int ACT, int MODE, bool EXTRA>
__global__ __launch_bounds__(256, 4) void mfma_gemm(const u16* __restrict__ A,
                                                    const u16* __restrict__ Wt,
                                                    const float* __restrict__ bias,
                                                    const float* __restrict__ extra,
                                                    void* __restrict__ Cout, int Ko) {
  __shared__ __align__(16) u16 Al[128 * 32];
  __shared__ __align__(16) u16 Bl[128 * 32];
  const int tid = threadIdx.x;
  const int lane = tid & 63, wave = tid >> 6;
  const int wr = wave >> 1, wc = wave & 1;
  const int l15 = lane & 15, l4 = lane >> 4;
  const size_t row0 = (size_t)blockIdx.y * 128;
  const int col0 = blockIdx.x * 128;
  const int q0 = wave * 64 + lane;
  const int q1 = q0 + 256;
  const u16* gA0 = A + (row0 + (q0 >> 2)) * K + (q0 & 3) * 8;
  const u16* gA1 = A + (row0 + (q1 >> 2)) * K + (q1 & 3) * 8;
  const u16* gB0 = Wt + (size_t)(col0 + (q0 >> 2)) * K + (q0 & 3) * 8;
  const u16* gB1 = Wt + (size_t)(col0 + (q1 >> 2)) * K + (q1 & 3) * 8;
  u16* lA0 = Al + wave * 512;
  u16* lA1 = Al + 2048 + wave * 512;
  u16* lB0 = Bl + wave * 512;
  u16* lB1 = Bl + 2048 + wave * 512;
  f32x4 acc[4][4];
#pragma unroll
  for (int i = 0; i < 4; i++)
#pragma unroll
    for (int j = 0; j < 4; j++) acc[i][j] = f32x4{0.f, 0.f, 0.f, 0.f};
#pragma unroll 1
  for (int k0 = 0; k0 < K; k0 += 32) {
    gload_lds16(gA0 + k0, lA0);
    gload_lds16(gA1 + k0, lA1);
    gload_lds16(gB0 + k0, lB0);
    gload_lds16(gB1 + k0, lB1);
    __syncthreads();
    bf16x8 af[4], bfr[4];
#pragma unroll
    for (int rb = 0; rb < 4; rb++)
      af[rb] = *(const bf16x8*)&Al[(wr * 64 + rb * 16 + l15) * 32 + l4 * 8];
#pragma unroll
    for (int cb = 0; cb < 4; cb++)
      bfr[cb] = *(const bf16x8*)&Bl[(wc * 64 + cb * 16 + l15) * 32 + l4 * 8];
#pragma unroll
    for (int rb = 0; rb < 4; rb++)
#pragma unroll
      for (int cb = 0; cb < 4; cb++)
        acc[rb][cb] = __builtin_amdgcn_mfma_f32_16x16x32_bf16(af[rb], bfr[cb], acc[rb][cb], 0, 0, 0);
    __syncthreads();
  }
#pragma unroll
  for (int rb = 0; rb < 4; rb++)
#pragma unroll
    for (int cb = 0; cb < 4; cb++)
#pragma unroll
      for (int r = 0; r < 4; r++) {
        size_t row = row0 + wr * 64 + rb * 16 + l4 * 4 + r;
        int col = col0 + wc * 64 + cb * 16 + l15;
        float v = acc[rb][cb][r] + bias[col];
        if (EXTRA) v += extra[((int)(row >> 15)) * 256 + col];
        if (ACT == 1) v = fmaxf(v, 0.f);
        else if (ACT == 2) v = 0.5f * v * (1.f + erff(v * 0.70710678118654752440f));
        else if (ACT == 3) v = 1.f / (1.f + __expf(-v));
        size_t o = row * (size_t)Ko + col;
        if (MODE == 0) ((float*)Cout)[o] = v;
        else if (MODE == 1) ((float*)Cout)[o] += v;
        else ((u16*)Cout)[o] = f2bf(v);
      }
}

// ---------------- full-row MFMA GEMM: 64 rows x 256 cols per block, resid += on xs -------
// EPI 1: row-LN -> hout bf16. EPI 2: scatter t -> hout[order[row]] + gt column partials.
template <int K, int EPI>
__global__ __launch_bounds__(256, 3) void mfma_row_gemm(const u16* __restrict__ A,
                                                        const u16* __restrict__ Wt,
                                                        const float* __restrict__ bias,
                                                        float* __restrict__ xs,
                                                        u16* __restrict__ hout,
                                                        const int* __restrict__ order,
                                                        const float* __restrict__ g,
                                                        const float* __restrict__ b,
                                                        float* __restrict__ gtpart,
                                                        int pbase) {
  __shared__ __align__(16) u16 Al[64 * 32];
  __shared__ __align__(16) u16 Bl[256 * 32];
  __shared__ float reds[2][4][64];
  const int tid = threadIdx.x;
  const int lane = tid & 63, wave = tid >> 6;
  const int l15 = lane & 15, l4 = lane >> 4;
  const size_t row0 = (size_t)blockIdx.x * 64;
  const u16* gA = A + (row0 + (tid >> 2)) * K + (tid & 3) * 8;
  u16* lA = Al + wave * 512;
  const u16* gB[4];
  u16* lB[4];
#pragma unroll
  for (int s = 0; s < 4; s++) {
    int q = s * 256 + tid;
    gB[s] = Wt + (size_t)(q >> 2) * K + (q & 3) * 8;
    lB[s] = Bl + s * 2048 + wave * 512;
  }
  f32x4 acc[4][4];
#pragma unroll
  for (int i = 0; i < 4; i++)
#pragma unroll
    for (int j = 0; j < 4; j++) acc[i][j] = f32x4{0.f, 0.f, 0.f, 0.f};
#pragma unroll 1
  for (int k0 = 0; k0 < K; k0 += 32) {
    gload_lds16(gA + k0, lA);
#pragma unroll
    for (int s = 0; s < 4; s++) gload_lds16(gB[s] + k0, lB[s]);
    __syncthreads();
    bf16x8 af[4], bfr[4];
#pragma unroll
    for (int rb = 0; rb < 4; rb++)
      af[rb] = *(const bf16x8*)&Al[(rb * 16 + l15) * 32 + l4 * 8];
#pragma unroll
    for (int cb = 0; cb < 4; cb++)
      bfr[cb] = *(const bf16x8*)&Bl[(wave * 64 + cb * 16 + l15) * 32 + l4 * 8];
#pragma unroll
    for (int rb = 0; rb < 4; rb++)
#pragma unroll
      for (int cb = 0; cb < 4; cb++)
        acc[rb][cb] = __builtin_amdgcn_mfma_f32_16x16x32_bf16(af[rb], bfr[cb], acc[rb][cb], 0, 0, 0);
    __syncthreads();
  }
  // epilogue: t = xs + v + bias; xs = t (keep t in acc)
#pragma unroll
  for (int rb = 0; rb < 4; rb++)
#pragma unroll
    for (int cb = 0; cb < 4; cb++)
#pragma unroll
      for (int r = 0; r < 4; r++) {
        size_t row = row0 + rb * 16 + l4 * 4 + r;
        int col = wave * 64 + cb * 16 + l15;
        size_t o = row * 256 + col;
        float t = xs[o] + acc[rb][cb][r] + bias[col];
        xs[o] = t;
        acc[rb][cb][r] = t;
      }
  if (EPI == 1) {
    float ps[4][4];
#pragma unroll
    for (int rb = 0; rb < 4; rb++)
#pragma unroll
      for (int r = 0; r < 4; r++) {
        float v = acc[rb][0][r] + acc[rb][1][r] + acc[rb][2][r] + acc[rb][3][r];
#pragma unroll
        for (int oo = 1; oo < 16; oo <<= 1) v += __shfl_xor(v, oo);
        ps[rb][r] = v;
      }
    if (l15 == 0)
#pragma unroll
      for (int rb = 0; rb < 4; rb++)
#pragma unroll
        for (int r = 0; r < 4; r++) reds[0][wave][rb * 16 + l4 * 4 + r] = ps[rb][r];
    __syncthreads();
    float mean[4][4];
#pragma unroll
    for (int rb = 0; rb < 4; rb++)
#pragma unroll
      for (int r = 0; r < 4; r++) {
        int ri = rb * 16 + l4 * 4 + r;
        mean[rb][r] = (reds[0][0][ri] + reds[0][1][ri] + reds[0][2][ri] + reds[0][3][ri]) *
                      (1.f / 256.f);
      }
#pragma unroll
    for (int rb = 0; rb < 4; rb++)
#pragma unroll
      for (int r = 0; r < 4; r++) {
        float d0 = acc[rb][0][r] - mean[rb][r], d1 = acc[rb][1][r] - mean[rb][r];
        float d2 = acc[rb][2][r] - mean[rb][r], d3 = acc[rb][3][r] - mean[rb][r];
        float v = d0 * d0 + d1 * d1 + d2 * d2 + d3 * d3;
#pragma unroll
        for (int oo = 1; oo < 16; oo <<= 1) v += __shfl_xor(v, oo);
        ps[rb][r] = v;
      }
    if (l15 == 0)
#pragma unroll
      for (int rb = 0; rb < 4; rb++)
#pragma unroll
        for (int r = 0; r < 4; r++) reds[1][wave][rb * 16 + l4 * 4 + r] = ps[rb][r];
    __syncthreads();
#pragma unroll
    for (int rb = 0; rb < 4; rb++)
#pragma unroll
      for (int r = 0; r < 4; r++) {
        int ri = rb * 16 + l4 * 4 + r;
        float var = (reds[1][0][ri] + reds[1][1][ri] + reds[1][2][ri] + reds[1][3][ri]) *
                    (1.f / 256.f);
        float inv = 1.f / sqrtf(var + LN_EPS);
        size_t row = row0 + ri;
#pragma unroll
        for (int cb = 0; cb < 4; cb++) {
          int col = wave * 64 + cb * 16 + l15;
          hout[row * 256 + col] =
              f2bf((acc[rb][cb][r] - mean[rb][r]) * inv * g[col] + b[col]);
        }
      }
  } else {
    // gt column partial sums over this block's 64 rows
#pragma unroll
    for (int cb = 0; cb < 4; cb++) {
      float cs = 0.f;
#pragma unroll
      for (int rb = 0; rb < 4; rb++)
#pragma unroll
        for (int r = 0; r < 4; r++) cs += acc[rb][cb][r];
      cs += __shfl_xor(cs, 16);
      cs += __shfl_xor(cs, 32);
      if (l4 == 0)
        gtpart[(size_t)(pbase + blockIdx.x) * 256 + wave * 64 + cb * 16 + l15] = cs;
    }
    // scatter to original order, bf16
#pragma unroll
    for (int rb = 0; rb < 4; rb++)
#pragma unroll
      for (int r = 0; r < 4; r++) {
        size_t row = row0 + rb * 16 + l4 * 4 + r;
        size_t dst = (size_t)order[row];
#pragma unroll
        for (int cb = 0; cb < 4; cb++) {
          int col = wave * 64 + cb * 16 + l15;
          hout[dst * 256 + col] = f2bf(acc[rb][cb][r]);
        }
      }
  }
}

// ---------------- fully-fused tail: 32 rows/block, K-chunk 64 (r10 measured-best) --------
__global__ __launch_bounds__(256, 2) void tail_kernel(
    const float* __restrict__ feats, const u16* __restrict__ xobf,
    const u16* __restrict__ ggw1T, const u16* __restrict__ fw1T,
    const u16* __restrict__ ggw2T, const u16* __restrict__ fw2T,
    const float* __restrict__ ggt, const float* __restrict__ fgt,
    const float* __restrict__ b1g, const float* __restrict__ b1f,
    const float* __restrict__ b2g, const float* __restrict__ b2f,
    float* __restrict__ out) {
  __shared__ __align__(16) u16 g1l[32 * 264];
  __shared__ __align__(16) u16 u1l[32 * 264];
  __shared__ __align__(16) u16 Bst[2][256 * 32];
  __shared__ __align__(16) u16 Ast[2][32 * 32];
  const int tid = threadIdx.x;
  const int lane = tid & 63, wave = tid >> 6;
  const int l15 = lane & 15, l4 = lane >> 4;
  const size_t row0 = (size_t)blockIdx.x * 32;
  const int cloud = (int)(row0 >> 15);
  f32x4 acc[2][4];

#pragma unroll
  for (int i = 0; i < 2; i++)
#pragma unroll
    for (int j = 0; j < 4; j++) acc[i][j] = f32x4{0.f, 0.f, 0.f, 0.f};
#pragma unroll 1
  for (int k0 = 0; k0 < 256; k0 += 64) {
    __syncthreads();
#pragma unroll
    for (int h = 0; h < 2; h++) {
#pragma unroll
      for (int s = 0; s < 4; s++) {
        int q = s * 256 + tid;
        gload_lds16(ggw1T + (size_t)(q >> 2) * 256 + k0 + h * 32 + (q & 3) * 8,
                    &Bst[h][0] + s * 2048 + wave * 512);
      }
      int r = tid >> 3, c4 = (tid & 7) * 4;
      float4 v = *(const float4*)(feats + (row0 + r) * 256 + k0 + h * 32 + c4);
      ushort4 o4; o4.x = f2bf(v.x); o4.y = f2bf(v.y); o4.z = f2bf(v.z); o4.w = f2bf(v.w);
      *(ushort4*)&Ast[h][r * 32 + c4] = o4;
    }
    __syncthreads();
#pragma unroll
    for (int h = 0; h < 2; h++) {
      bf16x8 af[2];
#pragma unroll
      for (int rb = 0; rb < 2; rb++)
        af[rb] = *(const bf16x8*)&Ast[h][(rb * 16 + l15) * 32 + l4 * 8];
#pragma unroll
      for (int cb = 0; cb < 4; cb++) {
        bf16x8 bf = *(const bf16x8*)&Bst[h][(wave * 64 + cb * 16 + l15) * 32 + l4 * 8];
#pragma unroll
        for (int rb = 0; rb < 2; rb++)
          acc[rb][cb] = __builtin_amdgcn_mfma_f32_16x16x32_bf16(af[rb], bf, acc[rb][cb], 0, 0, 0);
      }
    }
  }
#pragma unroll
  for (int rb = 0; rb < 2; rb++)
#pragma unroll
    for (int cb = 0; cb < 4; cb++)
#pragma unroll
      for (int r = 0; r < 4; r++) {
        int row = rb * 16 + l4 * 4 + r;
        int col = wave * 64 + cb * 16 + l15;
        float v = acc[rb][cb][r] + b1g[col] + ggt[cloud * 256 + col];
        g1l[row * 264 + col] = f2bf(fmaxf(v, 0.f));
      }
#pragma unroll
  for (int i = 0; i < 2; i++)
#pragma unroll
    for (int j = 0; j < 4; j++) acc[i][j] = f32x4{0.f, 0.f, 0.f, 0.f};
#pragma unroll 1
  for (int k0 = 0; k0 < 256; k0 += 64) {
    __syncthreads();
#pragma unroll
    for (int h = 0; h < 2; h++) {
#pragma unroll
      for (int s = 0; s < 4; s++) {
        int q = s * 256 + tid;
        gload_lds16(fw1T + (size_t)(q >> 2) * 256 + k0 + h * 32 + (q & 3) * 8,
                    &Bst[h][0] + s * 2048 + wave * 512);
      }
      if (tid < 128) {
        int q = tid;
        gload_lds16(xobf + (row0 + (q >> 2)) * 256 + k0 + h * 32 + (q & 3) * 8,
                    &Ast[h][0] + wave * 512);
      }
    }
    __syncthreads();
#pragma unroll
    for (int h = 0; h < 2; h++) {
      bf16x8 af[2];
#pragma unroll
      for (int rb = 0; rb < 2; rb++)
        af[rb] = *(const bf16x8*)&Ast[h][(rb * 16 + l15) * 32 + l4 * 8];
#pragma unroll
      for (int cb = 0; cb < 4; cb++) {
        bf16x8 bf = *(const bf16x8*)&Bst[h][(wave * 64 + cb * 16 + l15) * 32 + l4 * 8];
#pragma unroll
        for (int rb = 0; rb < 2; rb++)
          acc[rb][cb] = __builtin_amdgcn_mfma_f32_16x16x32_bf16(af[rb], bf, acc[rb][cb], 0, 0, 0);
      }
    }
  }
#pragma unroll
  for (int rb = 0; rb < 2; rb++)
#pragma unroll
    for (int cb = 0; cb < 4; cb++)
#pragma unroll
      for (int r = 0; r < 4; r++) {
        int row = rb * 16 + l4 * 4 + r;
        int col = wave * 64 + cb * 16 + l15;
        float v = acc[rb][cb][r] + b1f[col] + fgt[cloud * 256 + col];
        u1l[row * 264 + col] = f2bf(fmaxf(v, 0.f));
      }
#pragma unroll
  for (int i = 0; i < 2; i++)
#pragma unroll
    for (int j = 0; j < 4; j++) acc[i][j] = f32x4{0.f, 0.f, 0.f, 0.f};
#pragma unroll 1
  for (int k0 = 0; k0 < 256; k0 += 64) {
    __syncthreads();
#pragma unroll
    for (int h = 0; h < 2; h++)
#pragma unroll
      for (int s = 0; s < 4; s++) {
        int q = s * 256 + tid;
        gload_lds16(ggw2T + (size_t)(q >> 2) * 256 + k0 + h * 32 + (q & 3) * 8,
                    &Bst[h][0] + s * 2048 + wave * 512);
      }
    __syncthreads();
#pragma unroll
    for (int h = 0; h < 2; h++) {
      bf16x8 af[2];
#pragma unroll
      for (int rb = 0; rb < 2; rb++)
        af[rb] = *(const bf16x8*)&g1l[(rb * 16 + l15) * 264 + k0 + h * 32 + l4 * 8];
#pragma unroll
      for (int cb = 0; cb < 4; cb++) {
        bf16x8 bf = *(const bf16x8*)&Bst[h][(wave * 64 + cb * 16 + l15) * 32 + l4 * 8];
#pragma unroll
        for (int rb = 0; rb < 2; rb++)
          acc[rb][cb] = __builtin_amdgcn_mfma_f32_16x16x32_bf16(af[rb], bf, acc[rb][cb], 0, 0, 0);
      }
    }
  }
  float sg[2][4][4];
#pragma unroll
  for (int rb = 0; rb < 2; rb++)
#pragma unroll
    for (int cb = 0; cb < 4; cb++)
#pragma unroll
      for (int r = 0; r < 4; r++) {
        int col = wave * 64 + cb * 16 + l15;
        sg[rb][cb][r] = 1.f / (1.f + __expf(-(acc[rb][cb][r] + b2g[col])));
      }
#pragma unroll
  for (int i = 0; i < 2; i++)
#pragma unroll
    for (int j = 0; j < 4; j++) acc[i][j] = f32x4{0.f, 0.f, 0.f, 0.f};
#pragma unroll 1
  for (int k0 = 0; k0 < 256; k0 += 64) {
    __syncthreads();
#pragma unroll
    for (int h = 0; h < 2; h++)
#pragma unroll
      for (int s = 0; s < 4; s++) {
        int q = s * 256 + tid;
        gload_lds16(fw2T + (size_t)(q >> 2) * 256 + k0 + h * 32 + (q & 3) * 8,
                    &Bst[h][0] + s * 2048 + wave * 512);
      }
    __syncthreads();
#pragma unroll
    for (int h = 0; h < 2; h++) {
      bf16x8 af[2];
#pragma unroll
      for (int rb = 0; rb < 2; rb++)
        af[rb] = *(const bf16x8*)&u1l[(rb * 16 + l15) * 264 + k0 + h * 32 + l4 * 8];
#pragma unroll
      for (int cb = 0; cb < 4; cb++) {
        bf16x8 bf = *(const bf16x8*)&Bst[h][(wave * 64 + cb * 16 + l15) * 32 + l4 * 8];
#pragma unroll
        for (int rb = 0; rb < 2; rb++)
          acc[rb][cb] = __builtin_amdgcn_mfma_f32_16x16x32_bf16(af[rb], bf, acc[rb][cb], 0, 0, 0);
      }
    }
  }
#pragma unroll
  for (int rb = 0; rb < 2; rb++)
#pragma unroll
    for (int cb = 0; cb < 4; cb++)
#pragma unroll
      for (int r = 0; r < 4; r++) {
        size_t row = row0 + rb * 16 + l4 * 4 + r;
        int col = wave * 64 + cb * 16 + l15;
        size_t o = row * 256 + col;
        out[o] = feats[o] + sg[rb][cb][r] * (acc[rb][cb][r] + b2f[col]);
      }
}

// ---------------- MFMA attention: one (window, head) per block, 4 waves x 64 queries ----
__global__ __launch_bounds__(256, 3) void attn_mfma_kernel(const u16* __restrict__ qkv,
                                                           u16* __restrict__ ao) {
  __shared__ __align__(16) u16 VT[32 * 264];       // V^T [d][k], padded stride 264
  __shared__ __align__(16) u16 Pl[4][16 * 264];    // per-wave P [q][k]
  const int w = blockIdx.x, h = blockIdx.y;
  const int tid = threadIdx.x;
  const int lane = tid & 63, wave = tid >> 6;
  const int l15 = lane & 15, l4 = lane >> 4;
  const size_t base = (size_t)w * PATCH;
  {
    const u16* vrow = qkv + (base + tid) * 768 + 512 + h * HDIM;
#pragma unroll
    for (int d4 = 0; d4 < 8; d4++) {
      ushort4 v4 = *(const ushort4*)(vrow + d4 * 4);
      VT[(d4 * 4 + 0) * 264 + tid] = v4.x;
      VT[(d4 * 4 + 1) * 264 + tid] = v4.y;
      VT[(d4 * 4 + 2) * 264 + tid] = v4.z;
      VT[(d4 * 4 + 3) * 264 + tid] = v4.w;
    }
  }
  __syncthreads();
  u16* Pw = &Pl[wave][0];
  const float scale = 0.17677669529663687f;  // 1/sqrt(32)
  const f32x4 zero = {0.f, 0.f, 0.f, 0.f};
  for (int qt = 0; qt < 4; qt++) {
    const int qbase = wave * 64 + qt * 16;
    bf16x8 qf = *(const bf16x8*)(qkv + (base + qbase + l15) * 768 + h * HDIM + l4 * 8);
    f32x4 s[16];
#pragma unroll
    for (int kt = 0; kt < 16; kt++) {
      bf16x8 kf = *(const bf16x8*)(qkv + (base + kt * 16 + l15) * 768 + 256 + h * HDIM + l4 * 8);
      s[kt] = __builtin_amdgcn_mfma_f32_16x16x32_bf16(kf, qf, zero, 0, 0, 0);
    }
    float m = -1e30f;
#pragma unroll
    for (int kt = 0; kt < 16; kt++)
#pragma unroll
      for (int r = 0; r < 4; r++) { s[kt][r] *= scale; m = fmaxf(m, s[kt][r]); }
    m = fmaxf(m, __shfl_xor(m, 16));
    m = fmaxf(m, __shfl_xor(m, 32));
    float lsum = 0.f;
#pragma unroll
    for (int kt = 0; kt < 16; kt++) {
      float p0 = __expf(s[kt][0] - m), p1 = __expf(s[kt][1] - m);
      float p2 = __expf(s[kt][2] - m), p3 = __expf(s[kt][3] - m);
      lsum += (p0 + p1) + (p2 + p3);
      ushort4 pw4;
      pw4.x = f2bf(p0); pw4.y = f2bf(p1); pw4.z = f2bf(p2); pw4.w = f2bf(p3);
      *(ushort4*)&Pw[l15 * 264 + kt * 16 + l4 * 4] = pw4;
    }
    lsum += __shfl_xor(lsum, 16);
    lsum += __shfl_xor(lsum, 32);
    f32x4 o0 = zero, o1 = zero;
#pragma unroll
    for (int kc = 0; kc < 8; kc++) {
      bf16x8 pf = *(const bf16x8*)&Pw[l15 * 264 + kc * 32 + l4 * 8];
      bf16x8 va = *(const bf16x8*)&VT[l15 * 264 + kc * 32 + l4 * 8];
      bf16x8 vb = *(const bf16x8*)&VT[(16 + l15) * 264 + kc * 32 + l4 * 8];
      o0 = __builtin_amdgcn_mfma_f32_16x16x32_bf16(va, pf, o0, 0, 0, 0);
      o1 = __builtin_amdgcn_mfma_f32_16x16x32_bf16(vb, pf, o1, 0, 0, 0);
    }
    float inv = 1.f / lsum;
    u16* op = ao + (base + qbase + l15) * D_DIM + h * HDIM;
    ushort4 w0, w1;
    w0.x = f2bf(o0[0] * inv); w0.y = f2bf(o0[1] * inv);
    w0.z = f2bf(o0[2] * inv); w0.w = f2bf(o0[3] * inv);
    w1.x = f2bf(o1[0] * inv); w1.y = f2bf(o1[1] * inv);
    w1.z = f2bf(o1[2] * inv); w1.w = f2bf(o1[3] * inv);
    *(ushort4*)(op + l4 * 4) = w0;
    *(ushort4*)(op + 16 + l4 * 4) = w1;
  }
}

// ---------------- gt reduce from per-block column partials ----------------
__global__ __launch_bounds__(1024) void gt_reduce_kernel(const float* __restrict__ part,
                                                         float* __restrict__ gt) {
  const int c = blockIdx.x;
  const int col = threadIdx.x & 255, q = threadIdx.x >> 8;
  __shared__ float red[4][256];
  float s = 0.f;
  for (int i = q * 128; i < q * 128 + 128; i++)
    s += part[(size_t)(c * 512 + i) * 256 + col];
  red[q][col] = s;
  __syncthreads();
  if (q == 0)
    gt[c * 256 + col] =
        (red[0][col] + red[1][col] + red[2][col] + red[3][col]) * (1.f / (float)LPC);
}

// ---------------- per-cloud gt @ bottom-half weights (fp32) ----------------
__global__ __launch_bounds__(256) void pervec_kernel(const float* __restrict__ gt,
                                                     const float* __restrict__ ggw1,
                                                     const float* __restrict__ fw1,
                                                     float* __restrict__ ggt,
                                                     float* __restrict__ fgt) {
  const int c = blockIdx.x, which = blockIdx.y;
  const int t = threadIdx.x;
  const float* W = which ? fw1 : ggw1;
  float* o = which ? fgt : ggt;
  __shared__ float g[D_DIM];
  g[t] = gt[c * D_DIM + t];
  __syncthreads();
  float acc = 0.f;
#pragma unroll 8
  for (int k = 0; k < D_DIM; k++) acc += g[k] * W[(size_t)(256 + k) * D_DIM + t];
  o[c * D_DIM + t] = acc;
}

extern "C" void kernel_launch(void* const* d_in, const int* in_sizes, int n_in,
                              void* d_out, int out_size, void* d_ws, size_t ws_size,
                              hipStream_t stream) {
  const float* feats = (const float*)d_in[0];
  const float* coord = (const float*)d_in[1];
  const float* pe_w1 = (const float*)d_in[3];
  const float* pe_b1 = (const float*)d_in[4];
  const float* pe_w2 = (const float*)d_in[5];
  const float* pe_b2 = (const float*)d_in[6];
  const float* pre_g = (const float*)d_in[7];
  const float* pre_b = (const float*)d_in[8];
  const float* n1_g = (const float*)d_in[9];
  const float* n1_b = (const float*)d_in[10];
  const float* wqkv = (const float*)d_in[11];
  const float* bqkv = (const float*)d_in[12];
  const float* wo = (const float*)d_in[13];
  const float* bo = (const float*)d_in[14];
  const float* n2_g = (const float*)d_in[15];
  const float* n2_b = (const float*)d_in[16];
  const float* m_w1 = (const float*)d_in[17];
  const float* m_b1 = (const float*)d_in[18];
  const float* m_w2 = (const float*)d_in[19];
  const float* m_b2 = (const float*)d_in[20];
  const float* gg_w1 = (const float*)d_in[21];
  const float* gg_b1 = (const float*)d_in[22];
  const float* gg_w2 = (const float*)d_in[23];
  const float* gg_b2 = (const float*)d_in[24];
  const float* f_w1 = (const float*)d_in[25];
  const float* f_b1 = (const float*)d_in[26];
  const float* f_w2 = (const float*)d_in[27];
  const float* f_b2 = (const float*)d_in[28];
  float* out = (float*)d_out;

  // ---------------- workspace layout (~306 MiB) ----------------
  char* ws = (char*)d_ws;
  float* xs = (float*)(ws);                         // [0,128MiB) fp32 residual stream
  u16* hbuf = (u16*)(ws + 134217728);               // [128,192MiB) bf16 (ln1 / LN2)
  u16* qkvchunk = (u16*)(ws + 201326592);           // [192..240MiB) chunk qkv (48 MiB)
  u16* aochunk = (u16*)(ws + 251658240);            // [240..256MiB) chunk attn out (16 MiB)
  u16* tbuf = (u16*)(ws + 268435456);               // [256..288MiB) chunk MLP mid (32 MiB)
  u16* Hbuf = (u16*)(ws + 268435456);               // [N][64] bf16 (16 MiB, pre-attn only)
  u16* xobf = (u16*)(ws + 201326592);               // post-attn: bf16 xo (64 MiB)
  size_t off = 301989888;
  u64* keybuf = (u64*)(ws + off); off += (size_t)NTOT * 8;
  int* orderbuf = (int*)(ws + off); off += (size_t)NTOT * 4;
  int* rankbuf = (int*)(ws + off); off += (size_t)NTOT * 4;
  float* statsbuf = (float*)(ws + off); off += 4096;
  float* gtpart = (float*)(ws + off); off += (size_t)(NTOT / 64) * 256 * 4;  // 2 MiB
  float* gtbuf = (float*)(ws + off); off += 4096;
  float* ggtbuf = (float*)(ws + off); off += 4096;
  float* fgtbuf = (float*)(ws + off); off += 4096;
  u16* wqkvT = (u16*)(ws + off); off += 768 * 256 * 2;
  u16* woT = (u16*)(ws + off); off += 256 * 256 * 2;
  u16* mw1T = (u16*)(ws + off); off += 512 * 256 * 2;
  u16* mw2T = (u16*)(ws + off); off += 256 * 512 * 2;
  u16* ggw1T = (u16*)(ws + off); off += 256 * 256 * 2;
  u16* ggw2T = (u16*)(ws + off); off += 256 * 256 * 2;
  u16* fw1T = (u16*)(ws + off); off += 256 * 256 * 2;
  u16* fw2T = (u16*)(ws + off); off += 256 * 256 * 2;
  u16* pw2T = (u16*)(ws + off); off += 64 * 256 * 2;

  // 1. stats + keys + sort (8192-segment bitonic) + order/rank
  stats_kernel<<<NCLOUD, 256, 0, stream>>>(coord, statsbuf);
  key_kernel<<<NTOT / 256, 256, 0, stream>>>(coord, statsbuf, keybuf);
  sort_local8_kernel<<<NTOT / 8192, 1024, 0, stream>>>(keybuf);
  sort_global_kernel<<<NTOT / 512, 256, 0, stream>>>(keybuf, 16384, 8192);
  sort_finish8_kernel<<<NTOT / 8192, 1024, 0, stream>>>(keybuf, 16384);
  sort_global_kernel<<<NTOT / 512, 256, 0, stream>>>(keybuf, 32768, 16384);
  sort_global_kernel<<<NTOT / 512, 256, 0, stream>>>(keybuf, 32768, 8192);
  sort_finish8_kernel<<<NTOT / 8192, 1024, 0, stream>>>(keybuf, 32768);
  rank_kernel<<<NTOT / 256, 256, 0, stream>>>(keybuf, orderbuf, rankbuf);
  // 2. weight convert+transpose (bf16)
  wtrans_kernel<<<dim3(24, 8), 256, 0, stream>>>(wqkv, wqkvT, 256, 768);
  wtrans_kernel<<<dim3(8, 8), 256, 0, stream>>>(wo, woT, 256, 256);
  wtrans_kernel<<<dim3(16, 8), 256, 0, stream>>>(m_w1, mw1T, 256, 512);
  wtrans_kernel<<<dim3(8, 16), 256, 0, stream>>>(m_w2, mw2T, 512, 256);
  wtrans_kernel<<<dim3(8, 8), 256, 0, stream>>>(gg_w1, ggw1T, 256, 256);  // top half
  wtrans_kernel<<<dim3(8, 8), 256, 0, stream>>>(gg_w2, ggw2T, 256, 256);
  wtrans_kernel<<<dim3(8, 8), 256, 0, stream>>>(f_w1, fw1T, 256, 256);    // top half
  wtrans_kernel<<<dim3(8, 8), 256, 0, stream>>>(f_w2, fw2T, 256, 256);
  wtrans_kernel<<<dim3(8, 2), 256, 0, stream>>>(pe_w2, pw2T, 64, 256);
  // 3. PE + pre-LN + LN1, fully fused per 64-row tile:
  //    H = relu(scs@pw1+b1); pe = H@pw2+b2 (fp32); xs[rank]=LN_pre(feats+pe); hbuf[rank]=LN1
  h_kernel<<<NTOT * 64 / 256, 256, 0, stream>>>(coord, statsbuf, pe_w1, pe_b1, Hbuf);
  pe_row_kernel<<<NTOT / 64, 256, 0, stream>>>(Hbuf, pw2T, pe_b2, feats, rankbuf, pre_g,
                                               pre_b, n1_g, n1_b, xs, hbuf);
  // 4. attention block (chunked): xs += attn(ln1) @ wo + bo; proj also emits LN2 -> hbuf
  for (int ch = 0; ch < NCHUNK; ch++) {
    const size_t ro = (size_t)ch * CROWS;
    mfma_gemm<256, 0, 2, false><<<dim3(6, CROWS / 128), 256, 0, stream>>>(
        hbuf + ro * 256, wqkvT, bqkv, nullptr, qkvchunk, 768);
    attn_mfma_kernel<<<dim3(CROWS / PATCH, NHEAD), 256, 0, stream>>>(qkvchunk, aochunk);
    mfma_row_gemm<256, 1><<<CROWS / 64, 256, 0, stream>>>(
        aochunk, woT, bo, xs + ro * 256, hbuf + ro * 256, nullptr, n2_g, n2_b, nullptr, 0);
  }
  // 5. MLP block (chunked): xs += gelu(LN2@m_w1+b)@m_w2+b; MLP2 scatters -> xobf + gt partials
  for (int ch = 0; ch < NCHUNK; ch++) {
    const size_t ro = (size_t)ch * CROWS;
    mfma_gemm<256, 2, 2, false><<<dim3(MLPD / 128, CROWS / 128), 256, 0, stream>>>(
        hbuf + ro * 256, mw1T, m_b1, nullptr, tbuf, 512);
    mfma_row_gemm<512, 2><<<CROWS / 64, 256, 0, stream>>>(
        tbuf, mw2T, m_b2, xs + ro * 256, xobf, orderbuf + ro, nullptr, nullptr, gtpart,
        ch * (CROWS / 64));
  }
  // 6. global token from partials + per-cloud bottom-half weight vectors
  gt_reduce_kernel<<<NCLOUD, 1024, 0, stream>>>(gtpart, gtbuf);
  pervec_kernel<<<dim3(NCLOUD, 2), 256, 0, stream>>>(gtbuf, gg_w1, f_w1, ggtbuf, fgtbuf);
  // 7. fully-fused tail
  tail_kernel<<<NTOT / 32, 256, 0, stream>>>(feats, xobf, ggw1T, fw1T, ggw2T, fw2T,
                                             ggtbuf, fgtbuf, gg_b1, f_b1, gg_b2, f_b2, out);
  (void)in_sizes; (void)n_in; (void)out_size; (void)ws_size;
}

// Round 14
// 1277.519 us; speedup vs baseline: 1.0589x; 1.0589x over previous
//
#include <hip/hip_runtime.h>
#include <hip/hip_bf16.h>
#include <math.h>

#define D_DIM 256
#define NHEAD 8
#define HDIM 32
#define PATCH 256
#define NCLOUD 4
#define LPC 32768
#define NTOT (NCLOUD * LPC)
#define MLPD 512
#define PEHID 64
#define LN_EPS 1e-5f

typedef unsigned long long u64;
typedef unsigned short u16;
typedef short bf16x8 __attribute__((ext_vector_type(8)));  // 8 bf16 (4 VGPRs)
typedef float f32x4 __attribute__((ext_vector_type(4)));

__device__ __forceinline__ u16 f2bf(float x) {
  unsigned u = __float_as_uint(x);
  u += 0x7fffu + ((u >> 16) & 1u);
  return (u16)(u >> 16);
}
__device__ __forceinline__ float bf2f(u16 u) {
  return __uint_as_float(((unsigned)u) << 16);
}

// async global->LDS DMA, 16B per lane; lds ptr must be wave-uniform base (+lane*16 implicit)
__device__ __forceinline__ void gload_lds16(const u16* g, u16* l) {
  __builtin_amdgcn_global_load_lds((const __attribute__((address_space(1))) void*)g,
                                   (__attribute__((address_space(3))) void*)l, 16, 0, 0);
}

// ---------------- per-cloud coordinate stats ----------------
__global__ __launch_bounds__(256) void stats_kernel(const float* __restrict__ coord,
                                                    float* __restrict__ stats) {
  const int c = blockIdx.x, t = threadIdx.x;
  float sm[3] = {0.f, 0.f, 0.f};
  float mn[3] = {1e30f, 1e30f, 1e30f};
  float mx[3] = {-1e30f, -1e30f, -1e30f};
  const float* cp = coord + (size_t)c * LPC * 3;
  for (int i = t; i < LPC; i += 256) {
#pragma unroll
    for (int a = 0; a < 3; a++) {
      float v = cp[(size_t)i * 3 + a];
      sm[a] += v;
      mn[a] = fminf(mn[a], v);
      mx[a] = fmaxf(mx[a], v);
    }
  }
  __shared__ float sb[256];
  float rsum[3], rmn[3], rmx[3];
#pragma unroll
  for (int a = 0; a < 3; a++) {
    sb[t] = sm[a]; __syncthreads();
    for (int s = 128; s > 0; s >>= 1) { if (t < s) sb[t] += sb[t + s]; __syncthreads(); }
    rsum[a] = sb[0]; __syncthreads();
    sb[t] = mn[a]; __syncthreads();
    for (int s = 128; s > 0; s >>= 1) { if (t < s) sb[t] = fminf(sb[t], sb[t + s]); __syncthreads(); }
    rmn[a] = sb[0]; __syncthreads();
    sb[t] = mx[a]; __syncthreads();
    for (int s = 128; s > 0; s >>= 1) { if (t < s) sb[t] = fmaxf(sb[t], sb[t + s]); __syncthreads(); }
    rmx[a] = sb[0]; __syncthreads();
  }
  if (t == 0) {
    float* st = stats + c * 16;
#pragma unroll
    for (int a = 0; a < 3; a++) {
      float mean = rsum[a] / (float)LPC;
      st[a] = mean;
      st[3 + a] = fmaxf(fmaxf(rmx[a] - mean, mean - rmn[a]), 1e-6f);
      st[6 + a] = rmn[a];
      st[9 + a] = fmaxf(rmx[a] - rmn[a], 1e-6f);
    }
  }
}

// ---------------- serialization keys (bit-exact vs numpy; stable tie-break) ----------------
__global__ __launch_bounds__(256) void key_kernel(const float* __restrict__ coord,
                                                  const float* __restrict__ stats,
                                                  u64* __restrict__ keys) {
#pragma clang fp contract(off)
  const int g = blockIdx.x * 256 + threadIdx.x;
  const int c = g >> 15;
  const float* st = stats + c * 16;
  float k0 = (coord[(size_t)g * 3 + 0] - st[6]) / st[9];
  float k1 = (coord[(size_t)g * 3 + 1] - st[7]) / st[10];
  float k2 = (coord[(size_t)g * 3 + 2] - st[8]) / st[11];
  float key = k0 + 2.17f * k1;
  key = key + 3.31f * k2;
  keys[g] = ((u64)__float_as_uint(key) << 32) | (unsigned)(g & (LPC - 1));
}

// ---------------- bitonic sort: 8192-element LDS segments ----------------
__global__ __launch_bounds__(1024) void sort_local8_kernel(u64* __restrict__ keys) {
  __shared__ u64 s[8192];
  const int base = blockIdx.x * 8192;
  const int t = threadIdx.x;
  for (int i = t; i < 8192; i += 1024) s[i] = keys[base + i];
  __syncthreads();
  for (int k = 2; k <= 8192; k <<= 1) {
    for (int j = k >> 1; j > 0; j >>= 1) {
      for (int p = t; p < 4096; p += 1024) {
        int i = ((p & ~(j - 1)) << 1) | (p & (j - 1));
        int l = i | j;
        bool asc = (((base + i) & (LPC - 1)) & k) == 0;
        u64 a = s[i], bb = s[l];
        if (asc ? (a > bb) : (a < bb)) { s[i] = bb; s[l] = a; }
      }
      __syncthreads();
    }
  }
  for (int i = t; i < 8192; i += 1024) keys[base + i] = s[i];
}

__global__ __launch_bounds__(256) void sort_global_kernel(u64* __restrict__ keys, int k, int j) {
  int p = blockIdx.x * 256 + threadIdx.x;
  int i = ((p & ~(j - 1)) << 1) | (p & (j - 1));
  int l = i | j;
  bool asc = ((i & (LPC - 1)) & k) == 0;
  u64 a = keys[i], b = keys[l];
  if (asc ? (a > b) : (a < b)) { keys[i] = b; keys[l] = a; }
}

__global__ __launch_bounds__(1024) void sort_finish8_kernel(u64* __restrict__ keys, int k) {
  __shared__ u64 s[8192];
  const int base = blockIdx.x * 8192;
  const int t = threadIdx.x;
  for (int i = t; i < 8192; i += 1024) s[i] = keys[base + i];
  __syncthreads();
  for (int j = 4096; j > 0; j >>= 1) {
    for (int p = t; p < 4096; p += 1024) {
      int i = ((p & ~(j - 1)) << 1) | (p & (j - 1));
      int l = i | j;
      bool asc = (((base + i) & (LPC - 1)) & k) == 0;
      u64 a = s[i], bb = s[l];
      if (asc ? (a > bb) : (a < bb)) { s[i] = bb; s[l] = a; }
    }
    __syncthreads();
  }
  for (int i = t; i < 8192; i += 1024) keys[base + i] = s[i];
}

// final sort pass: finish the k=32768 merge AND emit order/rank directly (keys not written back)
__global__ __launch_bounds__(1024) void sort_final8_kernel(const u64* __restrict__ keys,
                                                           int k,
                                                           int* __restrict__ order,
                                                           int* __restrict__ rank) {
  __shared__ u64 s[8192];
  const int base = blockIdx.x * 8192;
  const int t = threadIdx.x;
  for (int i = t; i < 8192; i += 1024) s[i] = keys[base + i];
  __syncthreads();
  for (int j = 4096; j > 0; j >>= 1) {
    for (int p = t; p < 4096; p += 1024) {
      int i = ((p & ~(j - 1)) << 1) | (p & (j - 1));
      int l = i | j;
      bool asc = (((base + i) & (LPC - 1)) & k) == 0;
      u64 a = s[i], bb = s[l];
      if (asc ? (a > bb) : (a < bb)) { s[i] = bb; s[l] = a; }
    }
    __syncthreads();
  }
  for (int i = t; i < 8192; i += 1024) {
    int g = base + i;
    int src = (int)(unsigned)(s[i] & 0xffffffffULL) + (g & ~(LPC - 1));
    order[g] = src;
    rank[src] = g;
  }
}

// ---------------- merged weight transpose + fp32->bf16 (all 9 weights, one dispatch) -----
struct WtEntry { const float* src; u16* dst; int R; int C; int bstart; };
struct WtTable { WtEntry e[9]; int total; };

__global__ __launch_bounds__(256) void wtrans_all_kernel(WtTable tab) {
  __shared__ float t[32][33];
  int bid = blockIdx.x;
  int ei = 0;
#pragma unroll
  for (int i = 1; i < 9; i++)
    if (bid >= tab.e[i].bstart) ei = i;
  const WtEntry& E = tab.e[ei];
  int tile = bid - E.bstart;
  int tpr = E.C / 32;                 // tiles per row-band
  int bx = (tile % tpr) * 32, by = (tile / tpr) * 32;
  const int lc = threadIdx.x & 31, lr = threadIdx.x >> 5;  // 8 rows per pass
  for (int i = 0; i < 32; i += 8)
    t[lr + i][lc] = E.src[(size_t)(by + lr + i) * E.C + bx + lc];
  __syncthreads();
  for (int i = 0; i < 32; i += 8)
    E.dst[(size_t)(bx + lr + i) * E.R + by + lc] = f2bf(t[lc][lr + i]);
}

// ---------------- H = relu(scs @ pw1 + pb1), bf16 [N][64] ----------------
__global__ __launch_bounds__(256) void h_kernel(const float* __restrict__ coord,
                                                const float* __restrict__ stats,
                                                const float* __restrict__ pw1,
                                                const float* __restrict__ pb1,
                                                u16* __restrict__ H) {
  const int idx = blockIdx.x * 256 + threadIdx.x;
  const int row = idx >> 6, j = idx & 63;
  const int c = row >> 15;
  const float* st = stats + c * 16;
  float s0 = (coord[(size_t)row * 3 + 0] - st[0]) / st[3];
  float s1 = (coord[(size_t)row * 3 + 1] - st[1]) / st[4];
  float s2 = (coord[(size_t)row * 3 + 2] - st[2]) / st[5];
  float h = pb1[j] + s0 * pw1[j] + s1 * pw1[64 + j] + s2 * pw1[128 + j];
  H[idx] = f2bf(fmaxf(h, 0.f));
}

// ---------------- pe row GEMM + fused add+LN_pre+LN1: 64 rows/block ----------------
__global__ __launch_bounds__(256, 3) void pe_row_kernel(
    const u16* __restrict__ H, const u16* __restrict__ pw2T,
    const float* __restrict__ pb2, const float* __restrict__ feats,
    const int* __restrict__ rank,
    const float* __restrict__ g0, const float* __restrict__ b0,
    const float* __restrict__ g1, const float* __restrict__ b1,
    float* __restrict__ xs, u16* __restrict__ ln1out) {
  __shared__ __align__(16) u16 Al[64 * 32];
  __shared__ __align__(16) u16 Bl[256 * 32];
  __shared__ float reds[2][4][64];
  const int tid = threadIdx.x;
  const int lane = tid & 63, wave = tid >> 6;
  const int l15 = lane & 15, l4 = lane >> 4;
  const size_t row0 = (size_t)blockIdx.x * 64;
  const u16* gA = H + (row0 + (tid >> 2)) * 64 + (tid & 3) * 8;
  u16* lA = Al + wave * 512;
  const u16* gB[4];
  u16* lB[4];
#pragma unroll
  for (int s = 0; s < 4; s++) {
    int q = s * 256 + tid;
    gB[s] = pw2T + (size_t)(q >> 2) * 64 + (q & 3) * 8;
    lB[s] = Bl + s * 2048 + wave * 512;
  }
  f32x4 acc[4][4];
#pragma unroll
  for (int i = 0; i < 4; i++)
#pragma unroll
    for (int j = 0; j < 4; j++) acc[i][j] = f32x4{0.f, 0.f, 0.f, 0.f};
#pragma unroll 1
  for (int k0 = 0; k0 < 64; k0 += 32) {
    gload_lds16(gA + k0, lA);
#pragma unroll
    for (int s = 0; s < 4; s++) gload_lds16(gB[s] + k0, lB[s]);
    __syncthreads();
    bf16x8 af[4], bfr[4];
#pragma unroll
    for (int rb = 0; rb < 4; rb++)
      af[rb] = *(const bf16x8*)&Al[(rb * 16 + l15) * 32 + l4 * 8];
#pragma unroll
    for (int cb = 0; cb < 4; cb++)
      bfr[cb] = *(const bf16x8*)&Bl[(wave * 64 + cb * 16 + l15) * 32 + l4 * 8];
#pragma unroll
    for (int rb = 0; rb < 4; rb++)
#pragma unroll
      for (int cb = 0; cb < 4; cb++)
        acc[rb][cb] = __builtin_amdgcn_mfma_f32_16x16x32_bf16(af[rb], bfr[cb], acc[rb][cb], 0, 0, 0);
    __syncthreads();
  }
#pragma unroll
  for (int rb = 0; rb < 4; rb++)
#pragma unroll
    for (int cb = 0; cb < 4; cb++)
#pragma unroll
      for (int r = 0; r < 4; r++) {
        size_t row = row0 + rb * 16 + l4 * 4 + r;
        int col = wave * 64 + cb * 16 + l15;
        acc[rb][cb][r] = feats[row * 256 + col] + acc[rb][cb][r] + pb2[col];
      }
  float ps[4][4], mean[4][4];
#pragma unroll
  for (int rb = 0; rb < 4; rb++)
#pragma unroll
    for (int r = 0; r < 4; r++) {
      float v = acc[rb][0][r] + acc[rb][1][r] + acc[rb][2][r] + acc[rb][3][r];
#pragma unroll
      for (int oo = 1; oo < 16; oo <<= 1) v += __shfl_xor(v, oo);
      ps[rb][r] = v;
    }
  if (l15 == 0)
#pragma unroll
    for (int rb = 0; rb < 4; rb++)
#pragma unroll
      for (int r = 0; r < 4; r++) reds[0][wave][rb * 16 + l4 * 4 + r] = ps[rb][r];
  __syncthreads();
#pragma unroll
  for (int rb = 0; rb < 4; rb++)
#pragma unroll
    for (int r = 0; r < 4; r++) {
      int ri = rb * 16 + l4 * 4 + r;
      mean[rb][r] = (reds[0][0][ri] + reds[0][1][ri] + reds[0][2][ri] + reds[0][3][ri]) *
                    (1.f / 256.f);
    }
#pragma unroll
  for (int rb = 0; rb < 4; rb++)
#pragma unroll
    for (int r = 0; r < 4; r++) {
      float d0 = acc[rb][0][r] - mean[rb][r], d1 = acc[rb][1][r] - mean[rb][r];
      float d2 = acc[rb][2][r] - mean[rb][r], d3 = acc[rb][3][r] - mean[rb][r];
      float v = d0 * d0 + d1 * d1 + d2 * d2 + d3 * d3;
#pragma unroll
      for (int oo = 1; oo < 16; oo <<= 1) v += __shfl_xor(v, oo);
      ps[rb][r] = v;
    }
  if (l15 == 0)
#pragma unroll
    for (int rb = 0; rb < 4; rb++)
#pragma unroll
      for (int r = 0; r < 4; r++) reds[1][wave][rb * 16 + l4 * 4 + r] = ps[rb][r];
  __syncthreads();
#pragma unroll
  for (int rb = 0; rb < 4; rb++)
#pragma unroll
    for (int r = 0; r < 4; r++) {
      int ri = rb * 16 + l4 * 4 + r;
      float var = (reds[1][0][ri] + reds[1][1][ri] + reds[1][2][ri] + reds[1][3][ri]) *
                  (1.f / 256.f);
      float inv = 1.f / sqrtf(var + LN_EPS);
      size_t row = row0 + ri;
      size_t dst = (size_t)rank[row];
#pragma unroll
      for (int cb = 0; cb < 4; cb++) {
        int col = wave * 64 + cb * 16 + l15;
        float y = (acc[rb][cb][r] - mean[rb][r]) * inv * g0[col] + b0[col];
        acc[rb][cb][r] = y;
        xs[dst * 256 + col] = y;
      }
    }
#pragma unroll
  for (int rb = 0; rb < 4; rb++)
#pragma unroll
    for (int r = 0; r < 4; r++) {
      float v = acc[rb][0][r] + acc[rb][1][r] + acc[rb][2][r] + acc[rb][3][r];
#pragma unroll
      for (int oo = 1; oo < 16; oo <<= 1) v += __shfl_xor(v, oo);
      ps[rb][r] = v;
    }
  __syncthreads();
  if (l15 == 0)
#pragma unroll
    for (int rb = 0; rb < 4; rb++)
#pragma unroll
      for (int r = 0; r < 4; r++) reds[0][wave][rb * 16 + l4 * 4 + r] = ps[rb][r];
  __syncthreads();
#pragma unroll
  for (int rb = 0; rb < 4; rb++)
#pragma unroll
    for (int r = 0; r < 4; r++) {
      int ri = rb * 16 + l4 * 4 + r;
      mean[rb][r] = (reds[0][0][ri] + reds[0][1][ri] + reds[0][2][ri] + reds[0][3][ri]) *
                    (1.f / 256.f);
    }
#pragma unroll
  for (int rb = 0; rb < 4; rb++)
#pragma unroll
    for (int r = 0; r < 4; r++) {
      float d0 = acc[rb][0][r] - mean[rb][r], d1 = acc[rb][1][r] - mean[rb][r];
      float d2 = acc[rb][2][r] - mean[rb][r], d3 = acc[rb][3][r] - mean[rb][r];
      float v = d0 * d0 + d1 * d1 + d2 * d2 + d3 * d3;
#pragma unroll
      for (int oo = 1; oo < 16; oo <<= 1) v += __shfl_xor(v, oo);
      ps[rb][r] = v;
    }
  if (l15 == 0)
#pragma unroll
    for (int rb = 0; rb < 4; rb++)
#pragma unroll
      for (int r = 0; r < 4; r++) reds[1][wave][rb * 16 + l4 * 4 + r] = ps[rb][r];
  __syncthreads();
#pragma unroll
  for (int rb = 0; rb < 4; rb++)
#pragma unroll
    for (int r = 0; r < 4; r++) {
      int ri = rb * 16 + l4 * 4 + r;
      float var = (reds[1][0][ri] + reds[1][1][ri] + reds[1][2][ri] + reds[1][3][ri]) *
                  (1.f / 256.f);
      float inv = 1.f / sqrtf(var + LN_EPS);
      size_t row = row0 + ri;
      size_t dst = (size_t)rank[row];
#pragma unroll
      for (int cb = 0; cb < 4; cb++) {
        int col = wave * 64 + cb * 16 + l15;
        ln1out[dst * 256 + col] =
            f2bf((acc[rb][cb][r] - mean[rb][r]) * inv * g1[col] + b1[col]);
      }
    }
}

// ---------------- MFMA GEMM (m97 structure): C[M x Ko] = act(A@Wt^T + bias) ----------------
template <int K, int ACT, int MODE, bool EXTRA>
__global__ __launch_bounds__(256, 4) void mfma_gemm(const u16* __restrict__ A,
                                                    const u16* __restrict__ Wt,
                                                    const float* __restrict__ bias,
                                                    const float* __restrict__ extra,
                                                    void* __restrict__ Cout, int Ko) {
  __shared__ __align__(16) u16 Al[128 * 32];
  __shared__ __align__(16) u16 Bl[128 * 32];
  const int tid = threadIdx.x;
  const int lane = tid & 63, wave = tid >> 6;
  const int wr = wave >> 1, wc = wave & 1;
  const int l15 = lane & 15, l4 = lane >> 4;
  const size_t row0 = (size_t)blockIdx.y * 128;
  const int col0 = blockIdx.x * 128;
  const int q0 = wave * 64 + lane;
  const int q1 = q0 + 256;
  const u16* gA0 = A + (row0 + (q0 >> 2)) * K + (q0 & 3) * 8;
  const u16* gA1 = A + (row0 + (q1 >> 2)) * K + (q1 & 3) * 8;
  const u16* gB0 = Wt + (size_t)(col0 + (q0 >> 2)) * K + (q0 & 3) * 8;
  const u16* gB1 = Wt + (size_t)(col0 + (q1 >> 2)) * K + (q1 & 3) * 8;
  u16* lA0 = Al + wave * 512;
  u16* lA1 = Al + 2048 + wave * 512;
  u16* lB0 = Bl + wave * 512;
  u16* lB1 = Bl + 2048 + wave * 512;
  f32x4 acc[4][4];
#pragma unroll
  for (int i = 0; i < 4; i++)
#pragma unroll
    for (int j = 0; j < 4; j++) acc[i][j] = f32x4{0.f, 0.f, 0.f, 0.f};
#pragma unroll 1
  for (int k0 = 0; k0 < K; k0 += 32) {
    gload_lds16(gA0 + k0, lA0);
    gload_lds16(gA1 + k0, lA1);
    gload_lds16(gB0 + k0, lB0);
    gload_lds16(gB1 + k0, lB1);
    __syncthreads();
    bf16x8 af[4], bfr[4];
#pragma unroll
    for (int rb = 0; rb < 4; rb++)
      af[rb] = *(const bf16x8*)&Al[(wr * 64 + rb * 16 + l15) * 32 + l4 * 8];
#pragma unroll
    for (int cb = 0; cb < 4; cb++)
      bfr[cb] = *(const bf16x8*)&Bl[(wc * 64 + cb * 16 + l15) * 32 + l4 * 8];
#pragma unroll
    for (int rb = 0; rb < 4; rb++)
#pragma unroll
      for (int cb = 0; cb < 4; cb++)
        acc[rb][cb] = __builtin_amdgcn_mfma_f32_16x16x32_bf16(af[rb], bfr[cb], acc[rb][cb], 0, 0, 0);
    __syncthreads();
  }
#pragma unroll
  for (int rb = 0; rb < 4; rb++)
#pragma unroll
    for (int cb = 0; cb < 4; cb++)
#pragma unroll
      for (int r = 0; r < 4; r++) {
        size_t row = row0 + wr * 64 + rb * 16 + l4 * 4 + r;
        int col = col0 + wc * 64 + cb * 16 + l15;
        float v = acc[rb][cb][r] + bias[col];
        if (EXTRA) v += extra[((int)(row >> 15)) * 256 + col];
        if (ACT == 1) v = fmaxf(v, 0.f);
        else if (ACT == 2) v = 0.5f * v * (1.f + erff(v * 0.70710678118654752440f));
        else if (ACT == 3) v = 1.f / (1.f + __expf(-v));
        size_t o = row * (size_t)Ko + col;
        if (MODE == 0) ((float*)Cout)[o] = v;
        else if (MODE == 1) ((float*)Cout)[o] += v;
        else ((u16*)Cout)[o] = f2bf(v);
      }
}

// ---------------- full-row MFMA GEMM: 64 rows x 256 cols per block, resid += on xs -------
template <int K, int EPI>
__global__ __launch_bounds__(256, 3) void mfma_row_gemm(const u16* __restrict__ A,
                                                        const u16* __restrict__ Wt,
                                                        const float* __restrict__ bias,
                                                        float* __restrict__ xs,
                                                        u16* __restrict__ hout,
                                                        const int* __restrict__ order,
                                                        const float* __restrict__ g,
                                                        const float* __restrict__ b,
                                                        float* __restrict__ gtpart,
                                                        int pbase) {
  __shared__ __align__(16) u16 Al[64 * 32];
  __shared__ __align__(16) u16 Bl[256 * 32];
  __shared__ float reds[2][4][64];
  const int tid = threadIdx.x;
  const int lane = tid & 63, wave = tid >> 6;
  const int l15 = lane & 15, l4 = lane >> 4;
  const size_t row0 = (size_t)blockIdx.x * 64;
  const u16* gA = A + (row0 + (tid >> 2)) * K + (tid & 3) * 8;
  u16* lA = Al + wave * 512;
  const u16* gB[4];
  u16* lB[4];
#pragma unroll
  for (int s = 0; s < 4; s++) {
    int q = s * 256 + tid;
    gB[s] = Wt + (size_t)(q >> 2) * K + (q & 3) * 8;
    lB[s] = Bl + s * 2048 + wave * 512;
  }
  f32x4 acc[4][4];
#pragma unroll
  for (int i = 0; i < 4; i++)
#pragma unroll
    for (int j = 0; j < 4; j++) acc[i][j] = f32x4{0.f, 0.f, 0.f, 0.f};
#pragma unroll 1
  for (int k0 = 0; k0 < K; k0 += 32) {
    gload_lds16(gA + k0, lA);
#pragma unroll
    for (int s = 0; s < 4; s++) gload_lds16(gB[s] + k0, lB[s]);
    __syncthreads();
    bf16x8 af[4], bfr[4];
#pragma unroll
    for (int rb = 0; rb < 4; rb++)
      af[rb] = *(const bf16x8*)&Al[(rb * 16 + l15) * 32 + l4 * 8];
#pragma unroll
    for (int cb = 0; cb < 4; cb++)
      bfr[cb] = *(const bf16x8*)&Bl[(wave * 64 + cb * 16 + l15) * 32 + l4 * 8];
#pragma unroll
    for (int rb = 0; rb < 4; rb++)
#pragma unroll
      for (int cb = 0; cb < 4; cb++)
        acc[rb][cb] = __builtin_amdgcn_mfma_f32_16x16x32_bf16(af[rb], bfr[cb], acc[rb][cb], 0, 0, 0);
    __syncthreads();
  }
#pragma unroll
  for (int rb = 0; rb < 4; rb++)
#pragma unroll
    for (int cb = 0; cb < 4; cb++)
#pragma unroll
      for (int r = 0; r < 4; r++) {
        size_t row = row0 + rb * 16 + l4 * 4 + r;
        int col = wave * 64 + cb * 16 + l15;
        size_t o = row * 256 + col;
        float t = xs[o] + acc[rb][cb][r] + bias[col];
        xs[o] = t;
        acc[rb][cb][r] = t;
      }
  if (EPI == 1) {
    float ps[4][4];
#pragma unroll
    for (int rb = 0; rb < 4; rb++)
#pragma unroll
      for (int r = 0; r < 4; r++) {
        float v = acc[rb][0][r] + acc[rb][1][r] + acc[rb][2][r] + acc[rb][3][r];
#pragma unroll
        for (int oo = 1; oo < 16; oo <<= 1) v += __shfl_xor(v, oo);
        ps[rb][r] = v;
      }
    if (l15 == 0)
#pragma unroll
      for (int rb = 0; rb < 4; rb++)
#pragma unroll
        for (int r = 0; r < 4; r++) reds[0][wave][rb * 16 + l4 * 4 + r] = ps[rb][r];
    __syncthreads();
    float mean[4][4];
#pragma unroll
    for (int rb = 0; rb < 4; rb++)
#pragma unroll
      for (int r = 0; r < 4; r++) {
        int ri = rb * 16 + l4 * 4 + r;
        mean[rb][r] = (reds[0][0][ri] + reds[0][1][ri] + reds[0][2][ri] + reds[0][3][ri]) *
                      (1.f / 256.f);
      }
#pragma unroll
    for (int rb = 0; rb < 4; rb++)
#pragma unroll
      for (int r = 0; r < 4; r++) {
        float d0 = acc[rb][0][r] - mean[rb][r], d1 = acc[rb][1][r] - mean[rb][r];
        float d2 = acc[rb][2][r] - mean[rb][r], d3 = acc[rb][3][r] - mean[rb][r];
        float v = d0 * d0 + d1 * d1 + d2 * d2 + d3 * d3;
#pragma unroll
        for (int oo = 1; oo < 16; oo <<= 1) v += __shfl_xor(v, oo);
        ps[rb][r] = v;
      }
    if (l15 == 0)
#pragma unroll
      for (int rb = 0; rb < 4; rb++)
#pragma unroll
        for (int r = 0; r < 4; r++) reds[1][wave][rb * 16 + l4 * 4 + r] = ps[rb][r];
    __syncthreads();
#pragma unroll
    for (int rb = 0; rb < 4; rb++)
#pragma unroll
      for (int r = 0; r < 4; r++) {
        int ri = rb * 16 + l4 * 4 + r;
        float var = (reds[1][0][ri] + reds[1][1][ri] + reds[1][2][ri] + reds[1][3][ri]) *
                    (1.f / 256.f);
        float inv = 1.f / sqrtf(var + LN_EPS);
        size_t row = row0 + ri;
#pragma unroll
        for (int cb = 0; cb < 4; cb++) {
          int col = wave * 64 + cb * 16 + l15;
          hout[row * 256 + col] =
              f2bf((acc[rb][cb][r] - mean[rb][r]) * inv * g[col] + b[col]);
        }
      }
  } else {
#pragma unroll
    for (int cb = 0; cb < 4; cb++) {
      float cs = 0.f;
#pragma unroll
      for (int rb = 0; rb < 4; rb++)
#pragma unroll
        for (int r = 0; r < 4; r++) cs += acc[rb][cb][r];
      cs += __shfl_xor(cs, 16);
      cs += __shfl_xor(cs, 32);
      if (l4 == 0)
        gtpart[(size_t)(pbase + blockIdx.x) * 256 + wave * 64 + cb * 16 + l15] = cs;
    }
#pragma unroll
    for (int rb = 0; rb < 4; rb++)
#pragma unroll
      for (int r = 0; r < 4; r++) {
        size_t row = row0 + rb * 16 + l4 * 4 + r;
        size_t dst = (size_t)order[row];
#pragma unroll
        for (int cb = 0; cb < 4; cb++) {
          int col = wave * 64 + cb * 16 + l15;
          hout[dst * 256 + col] = f2bf(acc[rb][cb][r]);
        }
      }
  }
}

// ---------------- fully-fused tail: 32 rows/block, K-chunk 64 (r10 measured-best) --------
__global__ __launch_bounds__(256, 2) void tail_kernel(
    const float* __restrict__ feats, const u16* __restrict__ xobf,
    const u16* __restrict__ ggw1T, const u16* __restrict__ fw1T,
    const u16* __restrict__ ggw2T, const u16* __restrict__ fw2T,
    const float* __restrict__ ggt, const float* __restrict__ fgt,
    const float* __restrict__ b1g, const float* __restrict__ b1f,
    const float* __restrict__ b2g, const float* __restrict__ b2f,
    float* __restrict__ out) {
  __shared__ __align__(16) u16 g1l[32 * 264];
  __shared__ __align__(16) u16 u1l[32 * 264];
  __shared__ __align__(16) u16 Bst[2][256 * 32];
  __shared__ __align__(16) u16 Ast[2][32 * 32];
  const int tid = threadIdx.x;
  const int lane = tid & 63, wave = tid >> 6;
  const int l15 = lane & 15, l4 = lane >> 4;
  const size_t row0 = (size_t)blockIdx.x * 32;
  const int cloud = (int)(row0 >> 15);
  f32x4 acc[2][4];

#pragma unroll
  for (int i = 0; i < 2; i++)
#pragma unroll
    for (int j = 0; j < 4; j++) acc[i][j] = f32x4{0.f, 0.f, 0.f, 0.f};
#pragma unroll 1
  for (int k0 = 0; k0 < 256; k0 += 64) {
    __syncthreads();
#pragma unroll
    for (int h = 0; h < 2; h++) {
#pragma unroll
      for (int s = 0; s < 4; s++) {
        int q = s * 256 + tid;
        gload_lds16(ggw1T + (size_t)(q >> 2) * 256 + k0 + h * 32 + (q & 3) * 8,
                    &Bst[h][0] + s * 2048 + wave * 512);
      }
      int r = tid >> 3, c4 = (tid & 7) * 4;
      float4 v = *(const float4*)(feats + (row0 + r) * 256 + k0 + h * 32 + c4);
      ushort4 o4; o4.x = f2bf(v.x); o4.y = f2bf(v.y); o4.z = f2bf(v.z); o4.w = f2bf(v.w);
      *(ushort4*)&Ast[h][r * 32 + c4] = o4;
    }
    __syncthreads();
#pragma unroll
    for (int h = 0; h < 2; h++) {
      bf16x8 af[2];
#pragma unroll
      for (int rb = 0; rb < 2; rb++)
        af[rb] = *(const bf16x8*)&Ast[h][(rb * 16 + l15) * 32 + l4 * 8];
#pragma unroll
      for (int cb = 0; cb < 4; cb++) {
        bf16x8 bf = *(const bf16x8*)&Bst[h][(wave * 64 + cb * 16 + l15) * 32 + l4 * 8];
#pragma unroll
        for (int rb = 0; rb < 2; rb++)
          acc[rb][cb] = __builtin_amdgcn_mfma_f32_16x16x32_bf16(af[rb], bf, acc[rb][cb], 0, 0, 0);
      }
    }
  }
#pragma unroll
  for (int rb = 0; rb < 2; rb++)
#pragma unroll
    for (int cb = 0; cb < 4; cb++)
#pragma unroll
      for (int r = 0; r < 4; r++) {
        int row = rb * 16 + l4 * 4 + r;
        int col = wave * 64 + cb * 16 + l15;
        float v = acc[rb][cb][r] + b1g[col] + ggt[cloud * 256 + col];
        g1l[row * 264 + col] = f2bf(fmaxf(v, 0.f));
      }
#pragma unroll
  for (int i = 0; i < 2; i++)
#pragma unroll
    for (int j = 0; j < 4; j++) acc[i][j] = f32x4{0.f, 0.f, 0.f, 0.f};
#pragma unroll 1
  for (int k0 = 0; k0 < 256; k0 += 64) {
    __syncthreads();
#pragma unroll
    for (int h = 0; h < 2; h++) {
#pragma unroll
      for (int s = 0; s < 4; s++) {
        int q = s * 256 + tid;
        gload_lds16(fw1T + (size_t)(q >> 2) * 256 + k0 + h * 32 + (q & 3) * 8,
                    &Bst[h][0] + s * 2048 + wave * 512);
      }
      if (tid < 128) {
        int q = tid;
        gload_lds16(xobf + (row0 + (q >> 2)) * 256 + k0 + h * 32 + (q & 3) * 8,
                    &Ast[h][0] + wave * 512);
      }
    }
    __syncthreads();
#pragma unroll
    for (int h = 0; h < 2; h++) {
      bf16x8 af[2];
#pragma unroll
      for (int rb = 0; rb < 2; rb++)
        af[rb] = *(const bf16x8*)&Ast[h][(rb * 16 + l15) * 32 + l4 * 8];
#pragma unroll
      for (int cb = 0; cb < 4; cb++) {
        bf16x8 bf = *(const bf16x8*)&Bst[h][(wave * 64 + cb * 16 + l15) * 32 + l4 * 8];
#pragma unroll
        for (int rb = 0; rb < 2; rb++)
          acc[rb][cb] = __builtin_amdgcn_mfma_f32_16x16x32_bf16(af[rb], bf, acc[rb][cb], 0, 0, 0);
      }
    }
  }
#pragma unroll
  for (int rb = 0; rb < 2; rb++)
#pragma unroll
    for (int cb = 0; cb < 4; cb++)
#pragma unroll
      for (int r = 0; r < 4; r++) {
        int row = rb * 16 + l4 * 4 + r;
        int col = wave * 64 + cb * 16 + l15;
        float v = acc[rb][cb][r] + b1f[col] + fgt[cloud * 256 + col];
        u1l[row * 264 + col] = f2bf(fmaxf(v, 0.f));
      }
#pragma unroll
  for (int i = 0; i < 2; i++)
#pragma unroll
    for (int j = 0; j < 4; j++) acc[i][j] = f32x4{0.f, 0.f, 0.f, 0.f};
#pragma unroll 1
  for (int k0 = 0; k0 < 256; k0 += 64) {
    __syncthreads();
#pragma unroll
    for (int h = 0; h < 2; h++)
#pragma unroll
      for (int s = 0; s < 4; s++) {
        int q = s * 256 + tid;
        gload_lds16(ggw2T + (size_t)(q >> 2) * 256 + k0 + h * 32 + (q & 3) * 8,
                    &Bst[h][0] + s * 2048 + wave * 512);
      }
    __syncthreads();
#pragma unroll
    for (int h = 0; h < 2; h++) {
      bf16x8 af[2];
#pragma unroll
      for (int rb = 0; rb < 2; rb++)
        af[rb] = *(const bf16x8*)&g1l[(rb * 16 + l15) * 264 + k0 + h * 32 + l4 * 8];
#pragma unroll
      for (int cb = 0; cb < 4; cb++) {
        bf16x8 bf = *(const bf16x8*)&Bst[h][(wave * 64 + cb * 16 + l15) * 32 + l4 * 8];
#pragma unroll
        for (int rb = 0; rb < 2; rb++)
          acc[rb][cb] = __builtin_amdgcn_mfma_f32_16x16x32_bf16(af[rb], bf, acc[rb][cb], 0, 0, 0);
      }
    }
  }
  float sg[2][4][4];
#pragma unroll
  for (int rb = 0; rb < 2; rb++)
#pragma unroll
    for (int cb = 0; cb < 4; cb++)
#pragma unroll
      for (int r = 0; r < 4; r++) {
        int col = wave * 64 + cb * 16 + l15;
        sg[rb][cb][r] = 1.f / (1.f + __expf(-(acc[rb][cb][r] + b2g[col])));
      }
#pragma unroll
  for (int i = 0; i < 2; i++)
#pragma unroll
    for (int j = 0; j < 4; j++) acc[i][j] = f32x4{0.f, 0.f, 0.f, 0.f};
#pragma unroll 1
  for (int k0 = 0; k0 < 256; k0 += 64) {
    __syncthreads();
#pragma unroll
    for (int h = 0; h < 2; h++)
#pragma unroll
      for (int s = 0; s < 4; s++) {
        int q = s * 256 + tid;
        gload_lds16(fw2T + (size_t)(q >> 2) * 256 + k0 + h * 32 + (q & 3) * 8,
                    &Bst[h][0] + s * 2048 + wave * 512);
      }
    __syncthreads();
#pragma unroll
    for (int h = 0; h < 2; h++) {
      bf16x8 af[2];
#pragma unroll
      for (int rb = 0; rb < 2; rb++)
        af[rb] = *(const bf16x8*)&u1l[(rb * 16 + l15) * 264 + k0 + h * 32 + l4 * 8];
#pragma unroll
      for (int cb = 0; cb < 4; cb++) {
        bf16x8 bf = *(const bf16x8*)&Bst[h][(wave * 64 + cb * 16 + l15) * 32 + l4 * 8];
#pragma unroll
        for (int rb = 0; rb < 2; rb++)
          acc[rb][cb] = __builtin_amdgcn_mfma_f32_16x16x32_bf16(af[rb], bf, acc[rb][cb], 0, 0, 0);
      }
    }
  }
#pragma unroll
  for (int rb = 0; rb < 2; rb++)
#pragma unroll
    for (int cb = 0; cb < 4; cb++)
#pragma unroll
      for (int r = 0; r < 4; r++) {
        size_t row = row0 + rb * 16 + l4 * 4 + r;
        int col = wave * 64 + cb * 16 + l15;
        size_t o = row * 256 + col;
        out[o] = feats[o] + sg[rb][cb][r] * (acc[rb][cb][r] + b2f[col]);
      }
}

// ---------------- MFMA attention: one (window, head) per block, 4 waves x 64 queries ----
__global__ __launch_bounds__(256, 3) void attn_mfma_kernel(const u16* __restrict__ qkv,
                                                           u16* __restrict__ ao) {
  __shared__ __align__(16) u16 VT[32 * 264];       // V^T [d][k], padded stride 264
  __shared__ __align__(16) u16 Pl[4][16 * 264];    // per-wave P [q][k]
  const int w = blockIdx.x, h = blockIdx.y;
  const int tid = threadIdx.x;
  const int lane = tid & 63, wave = tid >> 6;
  const int l15 = lane & 15, l4 = lane >> 4;
  const size_t base = (size_t)w * PATCH;
  {
    const u16* vrow = qkv + (base + tid) * 768 + 512 + h * HDIM;
#pragma unroll
    for (int d4 = 0; d4 < 8; d4++) {
      ushort4 v4 = *(const ushort4*)(vrow + d4 * 4);
      VT[(d4 * 4 + 0) * 264 + tid] = v4.x;
      VT[(d4 * 4 + 1) * 264 + tid] = v4.y;
      VT[(d4 * 4 + 2) * 264 + tid] = v4.z;
      VT[(d4 * 4 + 3) * 264 + tid] = v4.w;
    }
  }
  __syncthreads();
  u16* Pw = &Pl[wave][0];
  const float scale = 0.17677669529663687f;  // 1/sqrt(32)
  const f32x4 zero = {0.f, 0.f, 0.f, 0.f};
  for (int qt = 0; qt < 4; qt++) {
    const int qbase = wave * 64 + qt * 16;
    bf16x8 qf = *(const bf16x8*)(qkv + (base + qbase + l15) * 768 + h * HDIM + l4 * 8);
    f32x4 s[16];
#pragma unroll
    for (int kt = 0; kt < 16; kt++) {
      bf16x8 kf = *(const bf16x8*)(qkv + (base + kt * 16 + l15) * 768 + 256 + h * HDIM + l4 * 8);
      s[kt] = __builtin_amdgcn_mfma_f32_16x16x32_bf16(kf, qf, zero, 0, 0, 0);
    }
    float m = -1e30f;
#pragma unroll
    for (int kt = 0; kt < 16; kt++)
#pragma unroll
      for (int r = 0; r < 4; r++) { s[kt][r] *= scale; m = fmaxf(m, s[kt][r]); }
    m = fmaxf(m, __shfl_xor(m, 16));
    m = fmaxf(m, __shfl_xor(m, 32));
    float lsum = 0.f;
#pragma unroll
    for (int kt = 0; kt < 16; kt++) {
      float p0 = __expf(s[kt][0] - m), p1 = __expf(s[kt][1] - m);
      float p2 = __expf(s[kt][2] - m), p3 = __expf(s[kt][3] - m);
      lsum += (p0 + p1) + (p2 + p3);
      ushort4 pw4;
      pw4.x = f2bf(p0); pw4.y = f2bf(p1); pw4.z = f2bf(p2); pw4.w = f2bf(p3);
      *(ushort4*)&Pw[l15 * 264 + kt * 16 + l4 * 4] = pw4;
    }
    lsum += __shfl_xor(lsum, 16);
    lsum += __shfl_xor(lsum, 32);
    f32x4 o0 = zero, o1 = zero;
#pragma unroll
    for (int kc = 0; kc < 8; kc++) {
      bf16x8 pf = *(const bf16x8*)&Pw[l15 * 264 + kc * 32 + l4 * 8];
      bf16x8 va = *(const bf16x8*)&VT[l15 * 264 + kc * 32 + l4 * 8];
      bf16x8 vb = *(const bf16x8*)&VT[(16 + l15) * 264 + kc * 32 + l4 * 8];
      o0 = __builtin_amdgcn_mfma_f32_16x16x32_bf16(va, pf, o0, 0, 0, 0);
      o1 = __builtin_amdgcn_mfma_f32_16x16x32_bf16(vb, pf, o1, 0, 0, 0);
    }
    float inv = 1.f / lsum;
    u16* op = ao + (base + qbase + l15) * D_DIM + h * HDIM;
    ushort4 w0, w1;
    w0.x = f2bf(o0[0] * inv); w0.y = f2bf(o0[1] * inv);
    w0.z = f2bf(o0[2] * inv); w0.w = f2bf(o0[3] * inv);
    w1.x = f2bf(o1[0] * inv); w1.y = f2bf(o1[1] * inv);
    w1.z = f2bf(o1[2] * inv); w1.w = f2bf(o1[3] * inv);
    *(ushort4*)(op + l4 * 4) = w0;
    *(ushort4*)(op + 16 + l4 * 4) = w1;
  }
}

// ---------------- gt reduce from per-block column partials ----------------
__global__ __launch_bounds__(1024) void gt_reduce_kernel(const float* __restrict__ part,
                                                         float* __restrict__ gt) {
  const int c = blockIdx.x;
  const int col = threadIdx.x & 255, q = threadIdx.x >> 8;
  __shared__ float red[4][256];
  float s = 0.f;
  for (int i = q * 128; i < q * 128 + 128; i++)
    s += part[(size_t)(c * 512 + i) * 256 + col];
  red[q][col] = s;
  __syncthreads();
  if (q == 0)
    gt[c * 256 + col] =
        (red[0][col] + red[1][col] + red[2][col] + red[3][col]) * (1.f / (float)LPC);
}

// ---------------- per-cloud gt @ bottom-half weights (fp32) ----------------
__global__ __launch_bounds__(256) void pervec_kernel(const float* __restrict__ gt,
                                                     const float* __restrict__ ggw1,
                                                     const float* __restrict__ fw1,
                                                     float* __restrict__ ggt,
                                                     float* __restrict__ fgt) {
  const int c = blockIdx.x, which = blockIdx.y;
  const int t = threadIdx.x;
  const float* W = which ? fw1 : ggw1;
  float* o = which ? fgt : ggt;
  __shared__ float g[D_DIM];
  g[t] = gt[c * D_DIM + t];
  __syncthreads();
  float acc = 0.f;
#pragma unroll 8
  for (int k = 0; k < D_DIM; k++) acc += g[k] * W[(size_t)(256 + k) * D_DIM + t];
  o[c * D_DIM + t] = acc;
}

extern "C" void kernel_launch(void* const* d_in, const int* in_sizes, int n_in,
                              void* d_out, int out_size, void* d_ws, size_t ws_size,
                              hipStream_t stream) {
  const float* feats = (const float*)d_in[0];
  const float* coord = (const float*)d_in[1];
  const float* pe_w1 = (const float*)d_in[3];
  const float* pe_b1 = (const float*)d_in[4];
  const float* pe_w2 = (const float*)d_in[5];
  const float* pe_b2 = (const float*)d_in[6];
  const float* pre_g = (const float*)d_in[7];
  const float* pre_b = (const float*)d_in[8];
  const float* n1_g = (const float*)d_in[9];
  const float* n1_b = (const float*)d_in[10];
  const float* wqkv = (const float*)d_in[11];
  const float* bqkv = (const float*)d_in[12];
  const float* wo = (const float*)d_in[13];
  const float* bo = (const float*)d_in[14];
  const float* n2_g = (const float*)d_in[15];
  const float* n2_b = (const float*)d_in[16];
  const float* m_w1 = (const float*)d_in[17];
  const float* m_b1 = (const float*)d_in[18];
  const float* m_w2 = (const float*)d_in[19];
  const float* m_b2 = (const float*)d_in[20];
  const float* gg_w1 = (const float*)d_in[21];
  const float* gg_b1 = (const float*)d_in[22];
  const float* gg_w2 = (const float*)d_in[23];
  const float* gg_b2 = (const float*)d_in[24];
  const float* f_w1 = (const float*)d_in[25];
  const float* f_b1 = (const float*)d_in[26];
  const float* f_w2 = (const float*)d_in[27];
  const float* f_b2 = (const float*)d_in[28];
  float* out = (float*)d_out;

  // ---------------- dynamic workspace layout: NCHUNK=2 if ws allows, else 4 --------------
  char* ws = (char*)d_ws;
  const size_t MB = 1048576;
  // big-chunk layout requires ~392 MiB
  const bool big = (ws_size >= 400 * MB);
  const int nchunk = big ? 2 : 4;
  const size_t crows = NTOT / nchunk;
  float* xs = (float*)(ws);                         // [0,128M)
  u16* hbuf = (u16*)(ws + 128 * MB);                // [128,192M)
  u16* qkvchunk = (u16*)(ws + 192 * MB);            // NC2: 96 MiB; NC4: 48 MiB
  u16* xobf = (u16*)(ws + 192 * MB);                // post-attn (qkv region dead)
  u16* aochunk;
  u16* tbuf;
  u16* Hbuf;
  size_t off;
  if (big) {
    aochunk = (u16*)(ws + 288 * MB);                // 32 MiB
    tbuf = (u16*)(ws + 320 * MB);                   // 64 MiB
    Hbuf = (u16*)(ws + 320 * MB);                   // alias (pre-attn only)
    off = 384 * MB;
  } else {
    aochunk = (u16*)(ws + 240 * MB);                // 16 MiB
    tbuf = (u16*)(ws + 256 * MB);                   // 32 MiB
    Hbuf = (u16*)(ws + 256 * MB);
    off = 288 * MB;
  }
  u64* keybuf = (u64*)(ws + off); off += (size_t)NTOT * 8;
  int* orderbuf = (int*)(ws + off); off += (size_t)NTOT * 4;
  int* rankbuf = (int*)(ws + off); off += (size_t)NTOT * 4;
  float* statsbuf = (float*)(ws + off); off += 4096;
  float* gtpart = (float*)(ws + off); off += (size_t)(NTOT / 64) * 256 * 4;  // 2 MiB
  float* gtbuf = (float*)(ws + off); off += 4096;
  float* ggtbuf = (float*)(ws + off); off += 4096;
  float* fgtbuf = (float*)(ws + off); off += 4096;
  u16* wqkvT = (u16*)(ws + off); off += 768 * 256 * 2;
  u16* woT = (u16*)(ws + off); off += 256 * 256 * 2;
  u16* mw1T = (u16*)(ws + off); off += 512 * 256 * 2;
  u16* mw2T = (u16*)(ws + off); off += 256 * 512 * 2;
  u16* ggw1T = (u16*)(ws + off); off += 256 * 256 * 2;
  u16* ggw2T = (u16*)(ws + off); off += 256 * 256 * 2;
  u16* fw1T = (u16*)(ws + off); off += 256 * 256 * 2;
  u16* fw2T = (u16*)(ws + off); off += 256 * 256 * 2;
  u16* pw2T = (u16*)(ws + off); off += 64 * 256 * 2;

  // 1. stats + keys + sort (8192-segment bitonic; final pass emits order/rank)
  stats_kernel<<<NCLOUD, 256, 0, stream>>>(coord, statsbuf);
  key_kernel<<<NTOT / 256, 256, 0, stream>>>(coord, statsbuf, keybuf);
  sort_local8_kernel<<<NTOT / 8192, 1024, 0, stream>>>(keybuf);
  sort_global_kernel<<<NTOT / 512, 256, 0, stream>>>(keybuf, 16384, 8192);
  sort_finish8_kernel<<<NTOT / 8192, 1024, 0, stream>>>(keybuf, 16384);
  sort_global_kernel<<<NTOT / 512, 256, 0, stream>>>(keybuf, 32768, 16384);
  sort_global_kernel<<<NTOT / 512, 256, 0, stream>>>(keybuf, 32768, 8192);
  sort_final8_kernel<<<NTOT / 8192, 1024, 0, stream>>>(keybuf, 32768, orderbuf, rankbuf);
  // 2. all weight transposes in one dispatch
  {
    WtTable tab;
    int b = 0;
    auto add = [&](int i, const float* s, u16* d, int R, int C) {
      tab.e[i] = {s, d, R, C, b};
      b += (C / 32) * (R / 32);
    };
    add(0, wqkv, wqkvT, 256, 768);
    add(1, wo, woT, 256, 256);
    add(2, m_w1, mw1T, 256, 512);
    add(3, m_w2, mw2T, 512, 256);
    add(4, gg_w1, ggw1T, 256, 256);   // top half
    add(5, gg_w2, ggw2T, 256, 256);
    add(6, f_w1, fw1T, 256, 256);     // top half
    add(7, f_w2, fw2T, 256, 256);
    add(8, pe_w2, pw2T, 64, 256);
    tab.total = b;
    wtrans_all_kernel<<<b, 256, 0, stream>>>(tab);
  }
  // 3. PE + pre-LN + LN1 fused per 64-row tile
  h_kernel<<<NTOT * 64 / 256, 256, 0, stream>>>(coord, statsbuf, pe_w1, pe_b1, Hbuf);
  pe_row_kernel<<<NTOT / 64, 256, 0, stream>>>(Hbuf, pw2T, pe_b2, feats, rankbuf, pre_g,
                                               pre_b, n1_g, n1_b, xs, hbuf);
  // 4. attention block (chunked): xs += attn(ln1) @ wo + bo; proj also emits LN2 -> hbuf
  for (int ch = 0; ch < nchunk; ch++) {
    const size_t ro = (size_t)ch * crows;
    mfma_gemm<256, 0, 2, false><<<dim3(6, crows / 128), 256, 0, stream>>>(
        hbuf + ro * 256, wqkvT, bqkv, nullptr, qkvchunk, 768);
    attn_mfma_kernel<<<dim3(crows / PATCH, NHEAD), 256, 0, stream>>>(qkvchunk, aochunk);
    mfma_row_gemm<256, 1><<<crows / 64, 256, 0, stream>>>(
        aochunk, woT, bo, xs + ro * 256, hbuf + ro * 256, nullptr, n2_g, n2_b, nullptr, 0);
  }
  // 5. MLP block (chunked): xs += gelu(LN2@m_w1+b)@m_w2+b; MLP2 scatters -> xobf + gt partials
  for (int ch = 0; ch < nchunk; ch++) {
    const size_t ro = (size_t)ch * crows;
    mfma_gemm<256, 2, 2, false><<<dim3(MLPD / 128, crows / 128), 256, 0, stream>>>(
        hbuf + ro * 256, mw1T, m_b1, nullptr, tbuf, 512);
    mfma_row_gemm<512, 2><<<crows / 64, 256, 0, stream>>>(
        tbuf, mw2T, m_b2, xs + ro * 256, xobf, orderbuf + ro, nullptr, nullptr, gtpart,
        ch * (int)(crows / 64));
  }
  // 6. global token from partials + per-cloud bottom-half weight vectors
  gt_reduce_kernel<<<NCLOUD, 1024, 0, stream>>>(gtpart, gtbuf);
  pervec_kernel<<<dim3(NCLOUD, 2), 256, 0, stream>>>(gtbuf, gg_w1, f_w1, ggtbuf, fgtbuf);
  // 7. fully-fused tail
  tail_kernel<<<NTOT / 32, 256, 0, stream>>>(feats, xobf, ggw1T, fw1T, ggw2T, fw2T,
                                             ggtbuf, fgtbuf, gg_b1, f_b1, gg_b2, f_b2, out);
  (void)in_sizes; (void)n_in; (void)out_size;
}

// Round 15
// 1253.287 us; speedup vs baseline: 1.0794x; 1.0193x over previous
//
#include <hip/hip_runtime.h>
#include <hip/hip_bf16.h>
#include <math.h>

#define D_DIM 256
#define NHEAD 8
#define HDIM 32
#define PATCH 256
#define NCLOUD 4
#define LPC 32768
#define NTOT (NCLOUD * LPC)
#define MLPD 512
#define PEHID 64
#define LN_EPS 1e-5f

typedef unsigned long long u64;
typedef unsigned short u16;
typedef short bf16x8 __attribute__((ext_vector_type(8)));  // 8 bf16 (4 VGPRs)
typedef float f32x4 __attribute__((ext_vector_type(4)));

__device__ __forceinline__ u16 f2bf(float x) {
  unsigned u = __float_as_uint(x);
  u += 0x7fffu + ((u >> 16) & 1u);
  return (u16)(u >> 16);
}
__device__ __forceinline__ float bf2f(u16 u) {
  return __uint_as_float(((unsigned)u) << 16);
}

// async global->LDS DMA, 16B per lane; lds ptr must be wave-uniform base (+lane*16 implicit)
__device__ __forceinline__ void gload_lds16(const u16* g, u16* l) {
  __builtin_amdgcn_global_load_lds((const __attribute__((address_space(1))) void*)g,
                                   (__attribute__((address_space(3))) void*)l, 16, 0, 0);
}

// ---------------- per-cloud coordinate stats ----------------
__global__ __launch_bounds__(256) void stats_kernel(const float* __restrict__ coord,
                                                    float* __restrict__ stats) {
  const int c = blockIdx.x, t = threadIdx.x;
  float sm[3] = {0.f, 0.f, 0.f};
  float mn[3] = {1e30f, 1e30f, 1e30f};
  float mx[3] = {-1e30f, -1e30f, -1e30f};
  const float* cp = coord + (size_t)c * LPC * 3;
  for (int i = t; i < LPC; i += 256) {
#pragma unroll
    for (int a = 0; a < 3; a++) {
      float v = cp[(size_t)i * 3 + a];
      sm[a] += v;
      mn[a] = fminf(mn[a], v);
      mx[a] = fmaxf(mx[a], v);
    }
  }
  __shared__ float sb[256];
  float rsum[3], rmn[3], rmx[3];
#pragma unroll
  for (int a = 0; a < 3; a++) {
    sb[t] = sm[a]; __syncthreads();
    for (int s = 128; s > 0; s >>= 1) { if (t < s) sb[t] += sb[t + s]; __syncthreads(); }
    rsum[a] = sb[0]; __syncthreads();
    sb[t] = mn[a]; __syncthreads();
    for (int s = 128; s > 0; s >>= 1) { if (t < s) sb[t] = fminf(sb[t], sb[t + s]); __syncthreads(); }
    rmn[a] = sb[0]; __syncthreads();
    sb[t] = mx[a]; __syncthreads();
    for (int s = 128; s > 0; s >>= 1) { if (t < s) sb[t] = fmaxf(sb[t], sb[t + s]); __syncthreads(); }
    rmx[a] = sb[0]; __syncthreads();
  }
  if (t == 0) {
    float* st = stats + c * 16;
#pragma unroll
    for (int a = 0; a < 3; a++) {
      float mean = rsum[a] / (float)LPC;
      st[a] = mean;
      st[3 + a] = fmaxf(fmaxf(rmx[a] - mean, mean - rmn[a]), 1e-6f);
      st[6 + a] = rmn[a];
      st[9 + a] = fmaxf(rmx[a] - rmn[a], 1e-6f);
    }
  }
}

// ---------------- serialization keys (bit-exact vs numpy; stable tie-break) ----------------
__global__ __launch_bounds__(256) void key_kernel(const float* __restrict__ coord,
                                                  const float* __restrict__ stats,
                                                  u64* __restrict__ keys) {
#pragma clang fp contract(off)
  const int g = blockIdx.x * 256 + threadIdx.x;
  const int c = g >> 15;
  const float* st = stats + c * 16;
  float k0 = (coord[(size_t)g * 3 + 0] - st[6]) / st[9];
  float k1 = (coord[(size_t)g * 3 + 1] - st[7]) / st[10];
  float k2 = (coord[(size_t)g * 3 + 2] - st[8]) / st[11];
  float key = k0 + 2.17f * k1;
  key = key + 3.31f * k2;
  keys[g] = ((u64)__float_as_uint(key) << 32) | (unsigned)(g & (LPC - 1));
}

// ---------------- bitonic sort: 8192-element LDS segments ----------------
__global__ __launch_bounds__(1024) void sort_local8_kernel(u64* __restrict__ keys) {
  __shared__ u64 s[8192];
  const int base = blockIdx.x * 8192;
  const int t = threadIdx.x;
  for (int i = t; i < 8192; i += 1024) s[i] = keys[base + i];
  __syncthreads();
  for (int k = 2; k <= 8192; k <<= 1) {
    for (int j = k >> 1; j > 0; j >>= 1) {
      for (int p = t; p < 4096; p += 1024) {
        int i = ((p & ~(j - 1)) << 1) | (p & (j - 1));
        int l = i | j;
        bool asc = (((base + i) & (LPC - 1)) & k) == 0;
        u64 a = s[i], bb = s[l];
        if (asc ? (a > bb) : (a < bb)) { s[i] = bb; s[l] = a; }
      }
      __syncthreads();
    }
  }
  for (int i = t; i < 8192; i += 1024) keys[base + i] = s[i];
}

__global__ __launch_bounds__(256) void sort_global_kernel(u64* __restrict__ keys, int k, int j) {
  int p = blockIdx.x * 256 + threadIdx.x;
  int i = ((p & ~(j - 1)) << 1) | (p & (j - 1));
  int l = i | j;
  bool asc = ((i & (LPC - 1)) & k) == 0;
  u64 a = keys[i], b = keys[l];
  if (asc ? (a > b) : (a < b)) { keys[i] = b; keys[l] = a; }
}

__global__ __launch_bounds__(1024) void sort_finish8_kernel(u64* __restrict__ keys, int k) {
  __shared__ u64 s[8192];
  const int base = blockIdx.x * 8192;
  const int t = threadIdx.x;
  for (int i = t; i < 8192; i += 1024) s[i] = keys[base + i];
  __syncthreads();
  for (int j = 4096; j > 0; j >>= 1) {
    for (int p = t; p < 4096; p += 1024) {
      int i = ((p & ~(j - 1)) << 1) | (p & (j - 1));
      int l = i | j;
      bool asc = (((base + i) & (LPC - 1)) & k) == 0;
      u64 a = s[i], bb = s[l];
      if (asc ? (a > bb) : (a < bb)) { s[i] = bb; s[l] = a; }
    }
    __syncthreads();
  }
  for (int i = t; i < 8192; i += 1024) keys[base + i] = s[i];
}

// final sort pass: finish the k=32768 merge AND emit order/rank directly (keys not written back)
__global__ __launch_bounds__(1024) void sort_final8_kernel(const u64* __restrict__ keys,
                                                           int k,
                                                           int* __restrict__ order,
                                                           int* __restrict__ rank) {
  __shared__ u64 s[8192];
  const int base = blockIdx.x * 8192;
  const int t = threadIdx.x;
  for (int i = t; i < 8192; i += 1024) s[i] = keys[base + i];
  __syncthreads();
  for (int j = 4096; j > 0; j >>= 1) {
    for (int p = t; p < 4096; p += 1024) {
      int i = ((p & ~(j - 1)) << 1) | (p & (j - 1));
      int l = i | j;
      bool asc = (((base + i) & (LPC - 1)) & k) == 0;
      u64 a = s[i], bb = s[l];
      if (asc ? (a > bb) : (a < bb)) { s[i] = bb; s[l] = a; }
    }
    __syncthreads();
  }
  for (int i = t; i < 8192; i += 1024) {
    int g = base + i;
    int src = (int)(unsigned)(s[i] & 0xffffffffULL) + (g & ~(LPC - 1));
    order[g] = src;
    rank[src] = g;
  }
}

// ---------------- merged weight transpose + fp32->bf16 (all 9 weights, one dispatch) -----
struct WtEntry { const float* src; u16* dst; int R; int C; int bstart; };
struct WtTable { WtEntry e[9]; int total; };

__global__ __launch_bounds__(256) void wtrans_all_kernel(WtTable tab) {
  __shared__ float t[32][33];
  int bid = blockIdx.x;
  int ei = 0;
#pragma unroll
  for (int i = 1; i < 9; i++)
    if (bid >= tab.e[i].bstart) ei = i;
  const WtEntry& E = tab.e[ei];
  int tile = bid - E.bstart;
  int tpr = E.C / 32;                 // tiles per row-band
  int bx = (tile % tpr) * 32, by = (tile / tpr) * 32;
  const int lc = threadIdx.x & 31, lr = threadIdx.x >> 5;  // 8 rows per pass
  for (int i = 0; i < 32; i += 8)
    t[lr + i][lc] = E.src[(size_t)(by + lr + i) * E.C + bx + lc];
  __syncthreads();
  for (int i = 0; i < 32; i += 8)
    E.dst[(size_t)(bx + lr + i) * E.R + by + lc] = f2bf(t[lc][lr + i]);
}

// ---------------- pe row GEMM + fused H + add+LN_pre+LN1: 64 rows/block ----------------
// H = relu(scs@pw1+b1) computed inline -> LDS; pe = H @ pw2T^T + b2 (K=64);
// t = feats + pe; xs[rank] = LN_pre(t); ln1[rank] = bf16(LN1)
__global__ __launch_bounds__(256, 3) void pe_row_kernel(
    const float* __restrict__ coord, const float* __restrict__ stats,
    const float* __restrict__ pw1, const float* __restrict__ pb1,
    const u16* __restrict__ pw2T,
    const float* __restrict__ pb2, const float* __restrict__ feats,
    const int* __restrict__ rank,
    const float* __restrict__ g0, const float* __restrict__ b0,
    const float* __restrict__ g1, const float* __restrict__ b1,
    float* __restrict__ xs, u16* __restrict__ ln1out) {
  __shared__ __align__(16) u16 Al[64 * 32];
  __shared__ __align__(16) u16 Bl[256 * 32];
  __shared__ float reds[2][4][64];
  const int tid = threadIdx.x;
  const int lane = tid & 63, wave = tid >> 6;
  const int l15 = lane & 15, l4 = lane >> 4;
  const size_t row0 = (size_t)blockIdx.x * 64;
  // per-thread H source: row = row0 + (tid>>2), cols j0..j0+7 within each 32-k chunk
  const int arow = (int)row0 + (tid >> 2);
  const int cld = arow >> 15;
  const float* st = stats + cld * 16;
  const float s0 = (coord[(size_t)arow * 3 + 0] - st[0]) / st[3];
  const float s1 = (coord[(size_t)arow * 3 + 1] - st[1]) / st[4];
  const float s2 = (coord[(size_t)arow * 3 + 2] - st[2]) / st[5];
  const int j0 = (tid & 3) * 8;
  const u16* gB[4];
  u16* lB[4];
#pragma unroll
  for (int s = 0; s < 4; s++) {
    int q = s * 256 + tid;
    gB[s] = pw2T + (size_t)(q >> 2) * 64 + (q & 3) * 8;
    lB[s] = Bl + s * 2048 + wave * 512;
  }
  f32x4 acc[4][4];
#pragma unroll
  for (int i = 0; i < 4; i++)
#pragma unroll
    for (int j = 0; j < 4; j++) acc[i][j] = f32x4{0.f, 0.f, 0.f, 0.f};
#pragma unroll 1
  for (int k0 = 0; k0 < 64; k0 += 32) {
    // inline H computation -> same linear Al slots the DMA would produce
    ushort4 h4a, h4b;
#pragma unroll
    for (int jj = 0; jj < 4; jj++) {
      int j = k0 + j0 + jj;
      float h = pb1[j] + s0 * pw1[j] + s1 * pw1[64 + j] + s2 * pw1[128 + j];
      ((u16*)&h4a)[jj] = f2bf(fmaxf(h, 0.f));
    }
#pragma unroll
    for (int jj = 0; jj < 4; jj++) {
      int j = k0 + j0 + 4 + jj;
      float h = pb1[j] + s0 * pw1[j] + s1 * pw1[64 + j] + s2 * pw1[128 + j];
      ((u16*)&h4b)[jj] = f2bf(fmaxf(h, 0.f));
    }
    *(ushort4*)&Al[tid * 8] = h4a;
    *(ushort4*)&Al[tid * 8 + 4] = h4b;
#pragma unroll
    for (int s = 0; s < 4; s++) gload_lds16(gB[s] + k0, lB[s]);
    __syncthreads();
    bf16x8 af[4], bfr[4];
#pragma unroll
    for (int rb = 0; rb < 4; rb++)
      af[rb] = *(const bf16x8*)&Al[(rb * 16 + l15) * 32 + l4 * 8];
#pragma unroll
    for (int cb = 0; cb < 4; cb++)
      bfr[cb] = *(const bf16x8*)&Bl[(wave * 64 + cb * 16 + l15) * 32 + l4 * 8];
#pragma unroll
    for (int rb = 0; rb < 4; rb++)
#pragma unroll
      for (int cb = 0; cb < 4; cb++)
        acc[rb][cb] = __builtin_amdgcn_mfma_f32_16x16x32_bf16(af[rb], bfr[cb], acc[rb][cb], 0, 0, 0);
    __syncthreads();
  }
#pragma unroll
  for (int rb = 0; rb < 4; rb++)
#pragma unroll
    for (int cb = 0; cb < 4; cb++)
#pragma unroll
      for (int r = 0; r < 4; r++) {
        size_t row = row0 + rb * 16 + l4 * 4 + r;
        int col = wave * 64 + cb * 16 + l15;
        acc[rb][cb][r] = feats[row * 256 + col] + acc[rb][cb][r] + pb2[col];
      }
  float ps[4][4], mean[4][4];
#pragma unroll
  for (int rb = 0; rb < 4; rb++)
#pragma unroll
    for (int r = 0; r < 4; r++) {
      float v = acc[rb][0][r] + acc[rb][1][r] + acc[rb][2][r] + acc[rb][3][r];
#pragma unroll
      for (int oo = 1; oo < 16; oo <<= 1) v += __shfl_xor(v, oo);
      ps[rb][r] = v;
    }
  if (l15 == 0)
#pragma unroll
    for (int rb = 0; rb < 4; rb++)
#pragma unroll
      for (int r = 0; r < 4; r++) reds[0][wave][rb * 16 + l4 * 4 + r] = ps[rb][r];
  __syncthreads();
#pragma unroll
  for (int rb = 0; rb < 4; rb++)
#pragma unroll
    for (int r = 0; r < 4; r++) {
      int ri = rb * 16 + l4 * 4 + r;
      mean[rb][r] = (reds[0][0][ri] + reds[0][1][ri] + reds[0][2][ri] + reds[0][3][ri]) *
                    (1.f / 256.f);
    }
#pragma unroll
  for (int rb = 0; rb < 4; rb++)
#pragma unroll
    for (int r = 0; r < 4; r++) {
      float d0 = acc[rb][0][r] - mean[rb][r], d1 = acc[rb][1][r] - mean[rb][r];
      float d2 = acc[rb][2][r] - mean[rb][r], d3 = acc[rb][3][r] - mean[rb][r];
      float v = d0 * d0 + d1 * d1 + d2 * d2 + d3 * d3;
#pragma unroll
      for (int oo = 1; oo < 16; oo <<= 1) v += __shfl_xor(v, oo);
      ps[rb][r] = v;
    }
  if (l15 == 0)
#pragma unroll
    for (int rb = 0; rb < 4; rb++)
#pragma unroll
      for (int r = 0; r < 4; r++) reds[1][wave][rb * 16 + l4 * 4 + r] = ps[rb][r];
  __syncthreads();
#pragma unroll
  for (int rb = 0; rb < 4; rb++)
#pragma unroll
    for (int r = 0; r < 4; r++) {
      int ri = rb * 16 + l4 * 4 + r;
      float var = (reds[1][0][ri] + reds[1][1][ri] + reds[1][2][ri] + reds[1][3][ri]) *
                  (1.f / 256.f);
      float inv = 1.f / sqrtf(var + LN_EPS);
      size_t row = row0 + ri;
      size_t dst = (size_t)rank[row];
#pragma unroll
      for (int cb = 0; cb < 4; cb++) {
        int col = wave * 64 + cb * 16 + l15;
        float y = (acc[rb][cb][r] - mean[rb][r]) * inv * g0[col] + b0[col];
        acc[rb][cb][r] = y;
        xs[dst * 256 + col] = y;
      }
    }
#pragma unroll
  for (int rb = 0; rb < 4; rb++)
#pragma unroll
    for (int r = 0; r < 4; r++) {
      float v = acc[rb][0][r] + acc[rb][1][r] + acc[rb][2][r] + acc[rb][3][r];
#pragma unroll
      for (int oo = 1; oo < 16; oo <<= 1) v += __shfl_xor(v, oo);
      ps[rb][r] = v;
    }
  __syncthreads();
  if (l15 == 0)
#pragma unroll
    for (int rb = 0; rb < 4; rb++)
#pragma unroll
      for (int r = 0; r < 4; r++) reds[0][wave][rb * 16 + l4 * 4 + r] = ps[rb][r];
  __syncthreads();
#pragma unroll
  for (int rb = 0; rb < 4; rb++)
#pragma unroll
    for (int r = 0; r < 4; r++) {
      int ri = rb * 16 + l4 * 4 + r;
      mean[rb][r] = (reds[0][0][ri] + reds[0][1][ri] + reds[0][2][ri] + reds[0][3][ri]) *
                    (1.f / 256.f);
    }
#pragma unroll
  for (int rb = 0; rb < 4; rb++)
#pragma unroll
    for (int r = 0; r < 4; r++) {
      float d0 = acc[rb][0][r] - mean[rb][r], d1 = acc[rb][1][r] - mean[rb][r];
      float d2 = acc[rb][2][r] - mean[rb][r], d3 = acc[rb][3][r] - mean[rb][r];
      float v = d0 * d0 + d1 * d1 + d2 * d2 + d3 * d3;
#pragma unroll
      for (int oo = 1; oo < 16; oo <<= 1) v += __shfl_xor(v, oo);
      ps[rb][r] = v;
    }
  if (l15 == 0)
#pragma unroll
    for (int rb = 0; rb < 4; rb++)
#pragma unroll
      for (int r = 0; r < 4; r++) reds[1][wave][rb * 16 + l4 * 4 + r] = ps[rb][r];
  __syncthreads();
#pragma unroll
  for (int rb = 0; rb < 4; rb++)
#pragma unroll
    for (int r = 0; r < 4; r++) {
      int ri = rb * 16 + l4 * 4 + r;
      float var = (reds[1][0][ri] + reds[1][1][ri] + reds[1][2][ri] + reds[1][3][ri]) *
                  (1.f / 256.f);
      float inv = 1.f / sqrtf(var + LN_EPS);
      size_t row = row0 + ri;
      size_t dst = (size_t)rank[row];
#pragma unroll
      for (int cb = 0; cb < 4; cb++) {
        int col = wave * 64 + cb * 16 + l15;
        ln1out[dst * 256 + col] =
            f2bf((acc[rb][cb][r] - mean[rb][r]) * inv * g1[col] + b1[col]);
      }
    }
}

// ---------------- MFMA GEMM (m97 structure): C[M x Ko] = act(A@Wt^T + bias) ----------------
template <int K, int ACT, int MODE, bool EXTRA>
__global__ __launch_bounds__(256, 4) void mfma_gemm(const u16* __restrict__ A,
                                                    const u16* __restrict__ Wt,
                                                    const float* __restrict__ bias,
                                                    const float* __restrict__ extra,
                                                    void* __restrict__ Cout, int Ko) {
  __shared__ __align__(16) u16 Al[128 * 32];
  __shared__ __align__(16) u16 Bl[128 * 32];
  const int tid = threadIdx.x;
  const int lane = tid & 63, wave = tid >> 6;
  const int wr = wave >> 1, wc = wave & 1;
  const int l15 = lane & 15, l4 = lane >> 4;
  const size_t row0 = (size_t)blockIdx.y * 128;
  const int col0 = blockIdx.x * 128;
  const int q0 = wave * 64 + lane;
  const int q1 = q0 + 256;
  const u16* gA0 = A + (row0 + (q0 >> 2)) * K + (q0 & 3) * 8;
  const u16* gA1 = A + (row0 + (q1 >> 2)) * K + (q1 & 3) * 8;
  const u16* gB0 = Wt + (size_t)(col0 + (q0 >> 2)) * K + (q0 & 3) * 8;
  const u16* gB1 = Wt + (size_t)(col0 + (q1 >> 2)) * K + (q1 & 3) * 8;
  u16* lA0 = Al + wave * 512;
  u16* lA1 = Al + 2048 + wave * 512;
  u16* lB0 = Bl + wave * 512;
  u16* lB1 = Bl + 2048 + wave * 512;
  f32x4 acc[4][4];
#pragma unroll
  for (int i = 0; i < 4; i++)
#pragma unroll
    for (int j = 0; j < 4; j++) acc[i][j] = f32x4{0.f, 0.f, 0.f, 0.f};
#pragma unroll 1
  for (int k0 = 0; k0 < K; k0 += 32) {
    gload_lds16(gA0 + k0, lA0);
    gload_lds16(gA1 + k0, lA1);
    gload_lds16(gB0 + k0, lB0);
    gload_lds16(gB1 + k0, lB1);
    __syncthreads();
    bf16x8 af[4], bfr[4];
#pragma unroll
    for (int rb = 0; rb < 4; rb++)
      af[rb] = *(const bf16x8*)&Al[(wr * 64 + rb * 16 + l15) * 32 + l4 * 8];
#pragma unroll
    for (int cb = 0; cb < 4; cb++)
      bfr[cb] = *(const bf16x8*)&Bl[(wc * 64 + cb * 16 + l15) * 32 + l4 * 8];
#pragma unroll
    for (int rb = 0; rb < 4; rb++)
#pragma unroll
      for (int cb = 0; cb < 4; cb++)
        acc[rb][cb] = __builtin_amdgcn_mfma_f32_16x16x32_bf16(af[rb], bfr[cb], acc[rb][cb], 0, 0, 0);
    __syncthreads();
  }
#pragma unroll
  for (int rb = 0; rb < 4; rb++)
#pragma unroll
    for (int cb = 0; cb < 4; cb++)
#pragma unroll
      for (int r = 0; r < 4; r++) {
        size_t row = row0 + wr * 64 + rb * 16 + l4 * 4 + r;
        int col = col0 + wc * 64 + cb * 16 + l15;
        float v = acc[rb][cb][r] + bias[col];
        if (EXTRA) v += extra[((int)(row >> 15)) * 256 + col];
        if (ACT == 1) v = fmaxf(v, 0.f);
        else if (ACT == 2) v = 0.5f * v * (1.f + erff(v * 0.70710678118654752440f));
        else if (ACT == 3) v = 1.f / (1.f + __expf(-v));
        size_t o = row * (size_t)Ko + col;
        if (MODE == 0) ((float*)Cout)[o] = v;
        else if (MODE == 1) ((float*)Cout)[o] += v;
        else ((u16*)Cout)[o] = f2bf(v);
      }
}

// ---------------- full-row MFMA GEMM: 64 rows x 256 cols per block, resid += on xs -------
// EPI 1: xs=t + row-LN -> hout bf16. EPI 2: (xs write dead, skipped) scatter + gt partials.
template <int K, int EPI>
__global__ __launch_bounds__(256, 3) void mfma_row_gemm(const u16* __restrict__ A,
                                                        const u16* __restrict__ Wt,
                                                        const float* __restrict__ bias,
                                                        float* __restrict__ xs,
                                                        u16* __restrict__ hout,
                                                        const int* __restrict__ order,
                                                        const float* __restrict__ g,
                                                        const float* __restrict__ b,
                                                        float* __restrict__ gtpart,
                                                        int pbase) {
  __shared__ __align__(16) u16 Al[64 * 32];
  __shared__ __align__(16) u16 Bl[256 * 32];
  __shared__ float reds[2][4][64];
  const int tid = threadIdx.x;
  const int lane = tid & 63, wave = tid >> 6;
  const int l15 = lane & 15, l4 = lane >> 4;
  const size_t row0 = (size_t)blockIdx.x * 64;
  const u16* gA = A + (row0 + (tid >> 2)) * K + (tid & 3) * 8;
  u16* lA = Al + wave * 512;
  const u16* gB[4];
  u16* lB[4];
#pragma unroll
  for (int s = 0; s < 4; s++) {
    int q = s * 256 + tid;
    gB[s] = Wt + (size_t)(q >> 2) * K + (q & 3) * 8;
    lB[s] = Bl + s * 2048 + wave * 512;
  }
  f32x4 acc[4][4];
#pragma unroll
  for (int i = 0; i < 4; i++)
#pragma unroll
    for (int j = 0; j < 4; j++) acc[i][j] = f32x4{0.f, 0.f, 0.f, 0.f};
#pragma unroll 1
  for (int k0 = 0; k0 < K; k0 += 32) {
    gload_lds16(gA + k0, lA);
#pragma unroll
    for (int s = 0; s < 4; s++) gload_lds16(gB[s] + k0, lB[s]);
    __syncthreads();
    bf16x8 af[4], bfr[4];
#pragma unroll
    for (int rb = 0; rb < 4; rb++)
      af[rb] = *(const bf16x8*)&Al[(rb * 16 + l15) * 32 + l4 * 8];
#pragma unroll
    for (int cb = 0; cb < 4; cb++)
      bfr[cb] = *(const bf16x8*)&Bl[(wave * 64 + cb * 16 + l15) * 32 + l4 * 8];
#pragma unroll
    for (int rb = 0; rb < 4; rb++)
#pragma unroll
      for (int cb = 0; cb < 4; cb++)
        acc[rb][cb] = __builtin_amdgcn_mfma_f32_16x16x32_bf16(af[rb], bfr[cb], acc[rb][cb], 0, 0, 0);
    __syncthreads();
  }
  // epilogue: t = xs + v + bias; keep t in acc; write xs only when still needed (EPI 1)
#pragma unroll
  for (int rb = 0; rb < 4; rb++)
#pragma unroll
    for (int cb = 0; cb < 4; cb++)
#pragma unroll
      for (int r = 0; r < 4; r++) {
        size_t row = row0 + rb * 16 + l4 * 4 + r;
        int col = wave * 64 + cb * 16 + l15;
        size_t o = row * 256 + col;
        float t = xs[o] + acc[rb][cb][r] + bias[col];
        if (EPI == 1) xs[o] = t;
        acc[rb][cb][r] = t;
      }
  if (EPI == 1) {
    float ps[4][4];
#pragma unroll
    for (int rb = 0; rb < 4; rb++)
#pragma unroll
      for (int r = 0; r < 4; r++) {
        float v = acc[rb][0][r] + acc[rb][1][r] + acc[rb][2][r] + acc[rb][3][r];
#pragma unroll
        for (int oo = 1; oo < 16; oo <<= 1) v += __shfl_xor(v, oo);
        ps[rb][r] = v;
      }
    if (l15 == 0)
#pragma unroll
      for (int rb = 0; rb < 4; rb++)
#pragma unroll
        for (int r = 0; r < 4; r++) reds[0][wave][rb * 16 + l4 * 4 + r] = ps[rb][r];
    __syncthreads();
    float mean[4][4];
#pragma unroll
    for (int rb = 0; rb < 4; rb++)
#pragma unroll
      for (int r = 0; r < 4; r++) {
        int ri = rb * 16 + l4 * 4 + r;
        mean[rb][r] = (reds[0][0][ri] + reds[0][1][ri] + reds[0][2][ri] + reds[0][3][ri]) *
                      (1.f / 256.f);
      }
#pragma unroll
    for (int rb = 0; rb < 4; rb++)
#pragma unroll
      for (int r = 0; r < 4; r++) {
        float d0 = acc[rb][0][r] - mean[rb][r], d1 = acc[rb][1][r] - mean[rb][r];
        float d2 = acc[rb][2][r] - mean[rb][r], d3 = acc[rb][3][r] - mean[rb][r];
        float v = d0 * d0 + d1 * d1 + d2 * d2 + d3 * d3;
#pragma unroll
        for (int oo = 1; oo < 16; oo <<= 1) v += __shfl_xor(v, oo);
        ps[rb][r] = v;
      }
    if (l15 == 0)
#pragma unroll
      for (int rb = 0; rb < 4; rb++)
#pragma unroll
        for (int r = 0; r < 4; r++) reds[1][wave][rb * 16 + l4 * 4 + r] = ps[rb][r];
    __syncthreads();
#pragma unroll
    for (int rb = 0; rb < 4; rb++)
#pragma unroll
      for (int r = 0; r < 4; r++) {
        int ri = rb * 16 + l4 * 4 + r;
        float var = (reds[1][0][ri] + reds[1][1][ri] + reds[1][2][ri] + reds[1][3][ri]) *
                    (1.f / 256.f);
        float inv = 1.f / sqrtf(var + LN_EPS);
        size_t row = row0 + ri;
#pragma unroll
        for (int cb = 0; cb < 4; cb++) {
          int col = wave * 64 + cb * 16 + l15;
          hout[row * 256 + col] =
              f2bf((acc[rb][cb][r] - mean[rb][r]) * inv * g[col] + b[col]);
        }
      }
  } else {
#pragma unroll
    for (int cb = 0; cb < 4; cb++) {
      float cs = 0.f;
#pragma unroll
      for (int rb = 0; rb < 4; rb++)
#pragma unroll
        for (int r = 0; r < 4; r++) cs += acc[rb][cb][r];
      cs += __shfl_xor(cs, 16);
      cs += __shfl_xor(cs, 32);
      if (l4 == 0)
        gtpart[(size_t)(pbase + blockIdx.x) * 256 + wave * 64 + cb * 16 + l15] = cs;
    }
#pragma unroll
    for (int rb = 0; rb < 4; rb++)
#pragma unroll
      for (int r = 0; r < 4; r++) {
        size_t row = row0 + rb * 16 + l4 * 4 + r;
        size_t dst = (size_t)order[row];
#pragma unroll
        for (int cb = 0; cb < 4; cb++) {
          int col = wave * 64 + cb * 16 + l15;
          hout[dst * 256 + col] = f2bf(acc[rb][cb][r]);
        }
      }
  }
}

// ---------------- fully-fused tail: 32 rows/block, K-chunk 64 (r10 measured-best) --------
__global__ __launch_bounds__(256, 2) void tail_kernel(
    const float* __restrict__ feats, const u16* __restrict__ xobf,
    const u16* __restrict__ ggw1T, const u16* __restrict__ fw1T,
    const u16* __restrict__ ggw2T, const u16* __restrict__ fw2T,
    const float* __restrict__ ggt, const float* __restrict__ fgt,
    const float* __restrict__ b1g, const float* __restrict__ b1f,
    const float* __restrict__ b2g, const float* __restrict__ b2f,
    float* __restrict__ out) {
  __shared__ __align__(16) u16 g1l[32 * 264];
  __shared__ __align__(16) u16 u1l[32 * 264];
  __shared__ __align__(16) u16 Bst[2][256 * 32];
  __shared__ __align__(16) u16 Ast[2][32 * 32];
  const int tid = threadIdx.x;
  const int lane = tid & 63, wave = tid >> 6;
  const int l15 = lane & 15, l4 = lane >> 4;
  const size_t row0 = (size_t)blockIdx.x * 32;
  const int cloud = (int)(row0 >> 15);
  f32x4 acc[2][4];

#pragma unroll
  for (int i = 0; i < 2; i++)
#pragma unroll
    for (int j = 0; j < 4; j++) acc[i][j] = f32x4{0.f, 0.f, 0.f, 0.f};
#pragma unroll 1
  for (int k0 = 0; k0 < 256; k0 += 64) {
    __syncthreads();
#pragma unroll
    for (int h = 0; h < 2; h++) {
#pragma unroll
      for (int s = 0; s < 4; s++) {
        int q = s * 256 + tid;
        gload_lds16(ggw1T + (size_t)(q >> 2) * 256 + k0 + h * 32 + (q & 3) * 8,
                    &Bst[h][0] + s * 2048 + wave * 512);
      }
      int r = tid >> 3, c4 = (tid & 7) * 4;
      float4 v = *(const float4*)(feats + (row0 + r) * 256 + k0 + h * 32 + c4);
      ushort4 o4; o4.x = f2bf(v.x); o4.y = f2bf(v.y); o4.z = f2bf(v.z); o4.w = f2bf(v.w);
      *(ushort4*)&Ast[h][r * 32 + c4] = o4;
    }
    __syncthreads();
#pragma unroll
    for (int h = 0; h < 2; h++) {
      bf16x8 af[2];
#pragma unroll
      for (int rb = 0; rb < 2; rb++)
        af[rb] = *(const bf16x8*)&Ast[h][(rb * 16 + l15) * 32 + l4 * 8];
#pragma unroll
      for (int cb = 0; cb < 4; cb++) {
        bf16x8 bf = *(const bf16x8*)&Bst[h][(wave * 64 + cb * 16 + l15) * 32 + l4 * 8];
#pragma unroll
        for (int rb = 0; rb < 2; rb++)
          acc[rb][cb] = __builtin_amdgcn_mfma_f32_16x16x32_bf16(af[rb], bf, acc[rb][cb], 0, 0, 0);
      }
    }
  }
#pragma unroll
  for (int rb = 0; rb < 2; rb++)
#pragma unroll
    for (int cb = 0; cb < 4; cb++)
#pragma unroll
      for (int r = 0; r < 4; r++) {
        int row = rb * 16 + l4 * 4 + r;
        int col = wave * 64 + cb * 16 + l15;
        float v = acc[rb][cb][r] + b1g[col] + ggt[cloud * 256 + col];
        g1l[row * 264 + col] = f2bf(fmaxf(v, 0.f));
      }
#pragma unroll
  for (int i = 0; i < 2; i++)
#pragma unroll
    for (int j = 0; j < 4; j++) acc[i][j] = f32x4{0.f, 0.f, 0.f, 0.f};
#pragma unroll 1
  for (int k0 = 0; k0 < 256; k0 += 64) {
    __syncthreads();
#pragma unroll
    for (int h = 0; h < 2; h++) {
#pragma unroll
      for (int s = 0; s < 4; s++) {
        int q = s * 256 + tid;
        gload_lds16(fw1T + (size_t)(q >> 2) * 256 + k0 + h * 32 + (q & 3) * 8,
                    &Bst[h][0] + s * 2048 + wave * 512);
      }
      if (tid < 128) {
        int q = tid;
        gload_lds16(xobf + (row0 + (q >> 2)) * 256 + k0 + h * 32 + (q & 3) * 8,
                    &Ast[h][0] + wave * 512);
      }
    }
    __syncthreads();
#pragma unroll
    for (int h = 0; h < 2; h++) {
      bf16x8 af[2];
#pragma unroll
      for (int rb = 0; rb < 2; rb++)
        af[rb] = *(const bf16x8*)&Ast[h][(rb * 16 + l15) * 32 + l4 * 8];
#pragma unroll
      for (int cb = 0; cb < 4; cb++) {
        bf16x8 bf = *(const bf16x8*)&Bst[h][(wave * 64 + cb * 16 + l15) * 32 + l4 * 8];
#pragma unroll
        for (int rb = 0; rb < 2; rb++)
          acc[rb][cb] = __builtin_amdgcn_mfma_f32_16x16x32_bf16(af[rb], bf, acc[rb][cb], 0, 0, 0);
      }
    }
  }
#pragma unroll
  for (int rb = 0; rb < 2; rb++)
#pragma unroll
    for (int cb = 0; cb < 4; cb++)
#pragma unroll
      for (int r = 0; r < 4; r++) {
        int row = rb * 16 + l4 * 4 + r;
        int col = wave * 64 + cb * 16 + l15;
        float v = acc[rb][cb][r] + b1f[col] + fgt[cloud * 256 + col];
        u1l[row * 264 + col] = f2bf(fmaxf(v, 0.f));
      }
#pragma unroll
  for (int i = 0; i < 2; i++)
#pragma unroll
    for (int j = 0; j < 4; j++) acc[i][j] = f32x4{0.f, 0.f, 0.f, 0.f};
#pragma unroll 1
  for (int k0 = 0; k0 < 256; k0 += 64) {
    __syncthreads();
#pragma unroll
    for (int h = 0; h < 2; h++)
#pragma unroll
      for (int s = 0; s < 4; s++) {
        int q = s * 256 + tid;
        gload_lds16(ggw2T + (size_t)(q >> 2) * 256 + k0 + h * 32 + (q & 3) * 8,
                    &Bst[h][0] + s * 2048 + wave * 512);
      }
    __syncthreads();
#pragma unroll
    for (int h = 0; h < 2; h++) {
      bf16x8 af[2];
#pragma unroll
      for (int rb = 0; rb < 2; rb++)
        af[rb] = *(const bf16x8*)&g1l[(rb * 16 + l15) * 264 + k0 + h * 32 + l4 * 8];
#pragma unroll
      for (int cb = 0; cb < 4; cb++) {
        bf16x8 bf = *(const bf16x8*)&Bst[h][(wave * 64 + cb * 16 + l15) * 32 + l4 * 8];
#pragma unroll
        for (int rb = 0; rb < 2; rb++)
          acc[rb][cb] = __builtin_amdgcn_mfma_f32_16x16x32_bf16(af[rb], bf, acc[rb][cb], 0, 0, 0);
      }
    }
  }
  float sg[2][4][4];
#pragma unroll
  for (int rb = 0; rb < 2; rb++)
#pragma unroll
    for (int cb = 0; cb < 4; cb++)
#pragma unroll
      for (int r = 0; r < 4; r++) {
        int col = wave * 64 + cb * 16 + l15;
        sg[rb][cb][r] = 1.f / (1.f + __expf(-(acc[rb][cb][r] + b2g[col])));
      }
#pragma unroll
  for (int i = 0; i < 2; i++)
#pragma unroll
    for (int j = 0; j < 4; j++) acc[i][j] = f32x4{0.f, 0.f, 0.f, 0.f};
#pragma unroll 1
  for (int k0 = 0; k0 < 256; k0 += 64) {
    __syncthreads();
#pragma unroll
    for (int h = 0; h < 2; h++)
#pragma unroll
      for (int s = 0; s < 4; s++) {
        int q = s * 256 + tid;
        gload_lds16(fw2T + (size_t)(q >> 2) * 256 + k0 + h * 32 + (q & 3) * 8,
                    &Bst[h][0] + s * 2048 + wave * 512);
      }
    __syncthreads();
#pragma unroll
    for (int h = 0; h < 2; h++) {
      bf16x8 af[2];
#pragma unroll
      for (int rb = 0; rb < 2; rb++)
        af[rb] = *(const bf16x8*)&u1l[(rb * 16 + l15) * 264 + k0 + h * 32 + l4 * 8];
#pragma unroll
      for (int cb = 0; cb < 4; cb++) {
        bf16x8 bf = *(const bf16x8*)&Bst[h][(wave * 64 + cb * 16 + l15) * 32 + l4 * 8];
#pragma unroll
        for (int rb = 0; rb < 2; rb++)
          acc[rb][cb] = __builtin_amdgcn_mfma_f32_16x16x32_bf16(af[rb], bf, acc[rb][cb], 0, 0, 0);
      }
    }
  }
#pragma unroll
  for (int rb = 0; rb < 2; rb++)
#pragma unroll
    for (int cb = 0; cb < 4; cb++)
#pragma unroll
      for (int r = 0; r < 4; r++) {
        size_t row = row0 + rb * 16 + l4 * 4 + r;
        int col = wave * 64 + cb * 16 + l15;
        size_t o = row * 256 + col;
        out[o] = feats[o] + sg[rb][cb][r] * (acc[rb][cb][r] + b2f[col]);
      }
}

// ---------------- MFMA attention: one (window, head) per block, 4 waves x 64 queries ----
__global__ __launch_bounds__(256, 3) void attn_mfma_kernel(const u16* __restrict__ qkv,
                                                           u16* __restrict__ ao) {
  __shared__ __align__(16) u16 VT[32 * 264];       // V^T [d][k], padded stride 264
  __shared__ __align__(16) u16 Pl[4][16 * 264];    // per-wave P [q][k]
  const int w = blockIdx.x, h = blockIdx.y;
  const int tid = threadIdx.x;
  const int lane = tid & 63, wave = tid >> 6;
  const int l15 = lane & 15, l4 = lane >> 4;
  const size_t base = (size_t)w * PATCH;
  {
    const u16* vrow = qkv + (base + tid) * 768 + 512 + h * HDIM;
#pragma unroll
    for (int d4 = 0; d4 < 8; d4++) {
      ushort4 v4 = *(const ushort4*)(vrow + d4 * 4);
      VT[(d4 * 4 + 0) * 264 + tid] = v4.x;
      VT[(d4 * 4 + 1) * 264 + tid] = v4.y;
      VT[(d4 * 4 + 2) * 264 + tid] = v4.z;
      VT[(d4 * 4 + 3) * 264 + tid] = v4.w;
    }
  }
  __syncthreads();
  u16* Pw = &Pl[wave][0];
  const float scale = 0.17677669529663687f;  // 1/sqrt(32)
  const f32x4 zero = {0.f, 0.f, 0.f, 0.f};
  for (int qt = 0; qt < 4; qt++) {
    const int qbase = wave * 64 + qt * 16;
    bf16x8 qf = *(const bf16x8*)(qkv + (base + qbase + l15) * 768 + h * HDIM + l4 * 8);
    f32x4 s[16];
#pragma unroll
    for (int kt = 0; kt < 16; kt++) {
      bf16x8 kf = *(const bf16x8*)(qkv + (base + kt * 16 + l15) * 768 + 256 + h * HDIM + l4 * 8);
      s[kt] = __builtin_amdgcn_mfma_f32_16x16x32_bf16(kf, qf, zero, 0, 0, 0);
    }
    float m = -1e30f;
#pragma unroll
    for (int kt = 0; kt < 16; kt++)
#pragma unroll
      for (int r = 0; r < 4; r++) { s[kt][r] *= scale; m = fmaxf(m, s[kt][r]); }
    m = fmaxf(m, __shfl_xor(m, 16));
    m = fmaxf(m, __shfl_xor(m, 32));
    float lsum = 0.f;
#pragma unroll
    for (int kt = 0; kt < 16; kt++) {
      float p0 = __expf(s[kt][0] - m), p1 = __expf(s[kt][1] - m);
      float p2 = __expf(s[kt][2] - m), p3 = __expf(s[kt][3] - m);
      lsum += (p0 + p1) + (p2 + p3);
      ushort4 pw4;
      pw4.x = f2bf(p0); pw4.y = f2bf(p1); pw4.z = f2bf(p2); pw4.w = f2bf(p3);
      *(ushort4*)&Pw[l15 * 264 + kt * 16 + l4 * 4] = pw4;
    }
    lsum += __shfl_xor(lsum, 16);
    lsum += __shfl_xor(lsum, 32);
    f32x4 o0 = zero, o1 = zero;
#pragma unroll
    for (int kc = 0; kc < 8; kc++) {
      bf16x8 pf = *(const bf16x8*)&Pw[l15 * 264 + kc * 32 + l4 * 8];
      bf16x8 va = *(const bf16x8*)&VT[l15 * 264 + kc * 32 + l4 * 8];
      bf16x8 vb = *(const bf16x8*)&VT[(16 + l15) * 264 + kc * 32 + l4 * 8];
      o0 = __builtin_amdgcn_mfma_f32_16x16x32_bf16(va, pf, o0, 0, 0, 0);
      o1 = __builtin_amdgcn_mfma_f32_16x16x32_bf16(vb, pf, o1, 0, 0, 0);
    }
    float inv = 1.f / lsum;
    u16* op = ao + (base + qbase + l15) * D_DIM + h * HDIM;
    ushort4 w0, w1;
    w0.x = f2bf(o0[0] * inv); w0.y = f2bf(o0[1] * inv);
    w0.z = f2bf(o0[2] * inv); w0.w = f2bf(o0[3] * inv);
    w1.x = f2bf(o1[0] * inv); w1.y = f2bf(o1[1] * inv);
    w1.z = f2bf(o1[2] * inv); w1.w = f2bf(o1[3] * inv);
    *(ushort4*)(op + l4 * 4) = w0;
    *(ushort4*)(op + 16 + l4 * 4) = w1;
  }
}

// ---------------- gt reduce from per-block column partials ----------------
__global__ __launch_bounds__(1024) void gt_reduce_kernel(const float* __restrict__ part,
                                                         float* __restrict__ gt) {
  const int c = blockIdx.x;
  const int col = threadIdx.x & 255, q = threadIdx.x >> 8;
  __shared__ float red[4][256];
  float s = 0.f;
  for (int i = q * 128; i < q * 128 + 128; i++)
    s += part[(size_t)(c * 512 + i) * 256 + col];
  red[q][col] = s;
  __syncthreads();
  if (q == 0)
    gt[c * 256 + col] =
        (red[0][col] + red[1][col] + red[2][col] + red[3][col]) * (1.f / (float)LPC);
}

// ---------------- per-cloud gt @ bottom-half weights (fp32) ----------------
__global__ __launch_bounds__(256) void pervec_kernel(const float* __restrict__ gt,
                                                     const float* __restrict__ ggw1,
                                                     const float* __restrict__ fw1,
                                                     float* __restrict__ ggt,
                                                     float* __restrict__ fgt) {
  const int c = blockIdx.x, which = blockIdx.y;
  const int t = threadIdx.x;
  const float* W = which ? fw1 : ggw1;
  float* o = which ? fgt : ggt;
  __shared__ float g[D_DIM];
  g[t] = gt[c * D_DIM + t];
  __syncthreads();
  float acc = 0.f;
#pragma unroll 8
  for (int k = 0; k < D_DIM; k++) acc += g[k] * W[(size_t)(256 + k) * D_DIM + t];
  o[c * D_DIM + t] = acc;
}

extern "C" void kernel_launch(void* const* d_in, const int* in_sizes, int n_in,
                              void* d_out, int out_size, void* d_ws, size_t ws_size,
                              hipStream_t stream) {
  const float* feats = (const float*)d_in[0];
  const float* coord = (const float*)d_in[1];
  const float* pe_w1 = (const float*)d_in[3];
  const float* pe_b1 = (const float*)d_in[4];
  const float* pe_w2 = (const float*)d_in[5];
  const float* pe_b2 = (const float*)d_in[6];
  const float* pre_g = (const float*)d_in[7];
  const float* pre_b = (const float*)d_in[8];
  const float* n1_g = (const float*)d_in[9];
  const float* n1_b = (const float*)d_in[10];
  const float* wqkv = (const float*)d_in[11];
  const float* bqkv = (const float*)d_in[12];
  const float* wo = (const float*)d_in[13];
  const float* bo = (const float*)d_in[14];
  const float* n2_g = (const float*)d_in[15];
  const float* n2_b = (const float*)d_in[16];
  const float* m_w1 = (const float*)d_in[17];
  const float* m_b1 = (const float*)d_in[18];
  const float* m_w2 = (const float*)d_in[19];
  const float* m_b2 = (const float*)d_in[20];
  const float* gg_w1 = (const float*)d_in[21];
  const float* gg_b1 = (const float*)d_in[22];
  const float* gg_w2 = (const float*)d_in[23];
  const float* gg_b2 = (const float*)d_in[24];
  const float* f_w1 = (const float*)d_in[25];
  const float* f_b1 = (const float*)d_in[26];
  const float* f_w2 = (const float*)d_in[27];
  const float* f_b2 = (const float*)d_in[28];
  float* out = (float*)d_out;

  // ---------------- dynamic workspace layout: NCHUNK=2 if ws allows, else 4 --------------
  char* ws = (char*)d_ws;
  const size_t MB = 1048576;
  const bool big = (ws_size >= 400 * MB);
  const int nchunk = big ? 2 : 4;
  const size_t crows = NTOT / nchunk;
  float* xs = (float*)(ws);                         // [0,128M)
  u16* hbuf = (u16*)(ws + 128 * MB);                // [128,192M)
  u16* qkvchunk = (u16*)(ws + 192 * MB);            // NC2: 96 MiB; NC4: 48 MiB
  u16* xobf = (u16*)(ws + 192 * MB);                // post-attn (qkv region dead)
  u16* aochunk;
  u16* tbuf;
  size_t off;
  if (big) {
    aochunk = (u16*)(ws + 288 * MB);                // 32 MiB
    tbuf = (u16*)(ws + 320 * MB);                   // 64 MiB
    off = 384 * MB;
  } else {
    aochunk = (u16*)(ws + 240 * MB);                // 16 MiB
    tbuf = (u16*)(ws + 256 * MB);                   // 32 MiB
    off = 288 * MB;
  }
  u64* keybuf = (u64*)(ws + off); off += (size_t)NTOT * 8;
  int* orderbuf = (int*)(ws + off); off += (size_t)NTOT * 4;
  int* rankbuf = (int*)(ws + off); off += (size_t)NTOT * 4;
  float* statsbuf = (float*)(ws + off); off += 4096;
  float* gtpart = (float*)(ws + off); off += (size_t)(NTOT / 64) * 256 * 4;  // 2 MiB
  float* gtbuf = (float*)(ws + off); off += 4096;
  float* ggtbuf = (float*)(ws + off); off += 4096;
  float* fgtbuf = (float*)(ws + off); off += 4096;
  u16* wqkvT = (u16*)(ws + off); off += 768 * 256 * 2;
  u16* woT = (u16*)(ws + off); off += 256 * 256 * 2;
  u16* mw1T = (u16*)(ws + off); off += 512 * 256 * 2;
  u16* mw2T = (u16*)(ws + off); off += 256 * 512 * 2;
  u16* ggw1T = (u16*)(ws + off); off += 256 * 256 * 2;
  u16* ggw2T = (u16*)(ws + off); off += 256 * 256 * 2;
  u16* fw1T = (u16*)(ws + off); off += 256 * 256 * 2;
  u16* fw2T = (u16*)(ws + off); off += 256 * 256 * 2;
  u16* pw2T = (u16*)(ws + off); off += 64 * 256 * 2;

  // 1. stats + keys + sort (8192-segment bitonic; final pass emits order/rank)
  stats_kernel<<<NCLOUD, 256, 0, stream>>>(coord, statsbuf);
  key_kernel<<<NTOT / 256, 256, 0, stream>>>(coord, statsbuf, keybuf);
  sort_local8_kernel<<<NTOT / 8192, 1024, 0, stream>>>(keybuf);
  sort_global_kernel<<<NTOT / 512, 256, 0, stream>>>(keybuf, 16384, 8192);
  sort_finish8_kernel<<<NTOT / 8192, 1024, 0, stream>>>(keybuf, 16384);
  sort_global_kernel<<<NTOT / 512, 256, 0, stream>>>(keybuf, 32768, 16384);
  sort_global_kernel<<<NTOT / 512, 256, 0, stream>>>(keybuf, 32768, 8192);
  sort_final8_kernel<<<NTOT / 8192, 1024, 0, stream>>>(keybuf, 32768, orderbuf, rankbuf);
  // 2. all weight transposes in one dispatch
  {
    WtTable tab;
    int b = 0;
    auto add = [&](int i, const float* s, u16* d, int R, int C) {
      tab.e[i] = {s, d, R, C, b};
      b += (C / 32) * (R / 32);
    };
    add(0, wqkv, wqkvT, 256, 768);
    add(1, wo, woT, 256, 256);
    add(2, m_w1, mw1T, 256, 512);
    add(3, m_w2, mw2T, 512, 256);
    add(4, gg_w1, ggw1T, 256, 256);   // top half
    add(5, gg_w2, ggw2T, 256, 256);
    add(6, f_w1, fw1T, 256, 256);     // top half
    add(7, f_w2, fw2T, 256, 256);
    add(8, pe_w2, pw2T, 64, 256);
    tab.total = b;
    wtrans_all_kernel<<<b, 256, 0, stream>>>(tab);
  }
  // 3. PE (H inline) + pre-LN + LN1 fused per 64-row tile
  pe_row_kernel<<<NTOT / 64, 256, 0, stream>>>(coord, statsbuf, pe_w1, pe_b1, pw2T, pe_b2,
                                               feats, rankbuf, pre_g, pre_b, n1_g, n1_b,
                                               xs, hbuf);
  // 4. attention block (chunked): xs += attn(ln1) @ wo + bo; proj also emits LN2 -> hbuf
  for (int ch = 0; ch < nchunk; ch++) {
    const size_t ro = (size_t)ch * crows;
    mfma_gemm<256, 0, 2, false><<<dim3(6, crows / 128), 256, 0, stream>>>(
        hbuf + ro * 256, wqkvT, bqkv, nullptr, qkvchunk, 768);
    attn_mfma_kernel<<<dim3(crows / PATCH, NHEAD), 256, 0, stream>>>(qkvchunk, aochunk);
    mfma_row_gemm<256, 1><<<crows / 64, 256, 0, stream>>>(
        aochunk, woT, bo, xs + ro * 256, hbuf + ro * 256, nullptr, n2_g, n2_b, nullptr, 0);
  }
  // 5. MLP block (chunked): gelu(LN2@m_w1+b)@m_w2+b; MLP2 scatters -> xobf + gt partials
  for (int ch = 0; ch < nchunk; ch++) {
    const size_t ro = (size_t)ch * crows;
    mfma_gemm<256, 2, 2, false><<<dim3(MLPD / 128, crows / 128), 256, 0, stream>>>(
        hbuf + ro * 256, mw1T, m_b1, nullptr, tbuf, 512);
    mfma_row_gemm<512, 2><<<crows / 64, 256, 0, stream>>>(
        tbuf, mw2T, m_b2, xs + ro * 256, xobf, orderbuf + ro, nullptr, nullptr, gtpart,
        ch * (int)(crows / 64));
  }
  // 6. global token from partials + per-cloud bottom-half weight vectors
  gt_reduce_kernel<<<NCLOUD, 1024, 0, stream>>>(gtpart, gtbuf);
  pervec_kernel<<<dim3(NCLOUD, 2), 256, 0, stream>>>(gtbuf, gg_w1, f_w1, ggtbuf, fgtbuf);
  // 7. fully-fused tail
  tail_kernel<<<NTOT / 32, 256, 0, stream>>>(feats, xobf, ggw1T, fw1T, ggw2T, fw2T,
                                             ggtbuf, fgtbuf, gg_b1, f_b1, gg_b2, f_b2, out);
  (void)in_sizes; (void)n_in; (void)out_size;
}